// Round 20
// baseline (1281.172 us; speedup 1.0000x reference)
//
#include <hip/hip_runtime.h>

#define NSEQ   30000
#define NPAD   30208
#define FPAD   208
#define DMODEL 1024
#define NHEAD  8
#define DHEAD  64
#define LM     256
#define LCHUNK 118
#define INNER  512
#define NCHUNK 59     // NPAD / 512
#define NIT    4      // Newton-Schulz iterations (E'≈0.75E³; eps4 ~1e-5 << bf16 noise)

typedef long long ll;
typedef unsigned short us;
typedef unsigned int uint32;
typedef __attribute__((ext_vector_type(8))) __bf16 bf16x8;
typedef __attribute__((ext_vector_type(4))) float f32x4;

__device__ __forceinline__ float b2f(us u) {
    union { unsigned int i; float f; } x; x.i = ((unsigned int)u) << 16; return x.f;
}
__device__ __forceinline__ us f2b(float f) {
    union { float f; unsigned int i; } x; x.f = f;
    unsigned int r = x.i + 0x7fffu + ((x.i >> 16) & 1u);
    return (us)(r >> 16);
}
__device__ __forceinline__ void gload16(const us* g, us* l) {
    __builtin_amdgcn_global_load_lds(
        (__attribute__((address_space(1))) void*)(const_cast<us*>(g)),
        (__attribute__((address_space(3))) void*)l, 16, 0, 0);
}

// ---------------------------------------------------------------------------
// bf16 MFMA GEMM, 128x128 tile, BK=32, 4 waves, 2-phase dbuf + counted vmcnt
// + XCD-bijective swizzle. EPI: 3 QKV scatter (q*0.125); 10 C2=bf16(acc+bias);
// 12 C2=bf16(acc+bias+addp)
// ---------------------------------------------------------------------------
template<int EPI>
__global__ __launch_bounds__(256)
void bgemm(const us* __restrict__ A, const us* __restrict__ Bt,
           float* __restrict__ C, us* __restrict__ C2,
           const float* __restrict__ bias, const float* __restrict__ addp,
           int Mm, int Nn, int Kk, int lda, int ldb, int ldc, int ldadd,
           int Mstore, int Nstore, int rSub)
{
    __shared__ us As[2][128 * 32];
    __shared__ us Bs[2][128 * 32];

    int nwg = gridDim.x * gridDim.y;
    int orig = blockIdx.y * gridDim.x + blockIdx.x;
    int qd = nwg >> 3, rm = nwg & 7;
    int xcd = orig & 7, off = orig >> 3;
    int swz = (xcd < rm ? xcd * (qd + 1) : rm * (qd + 1) + (xcd - rm) * qd) + off;
    int by = swz / gridDim.x, bx = swz - by * gridDim.x;
    int m0 = by * 128, n0 = bx * 128;

    int tid = threadIdx.x, w = tid >> 6, lane = tid & 63;
    int wr = w >> 1, wc = w & 1;
    int nkt = Kk >> 5;

    int q0 = w * 128;
    int qa0 = q0 + lane, qa1 = q0 + 64 + lane;
    int r0s = qa0 >> 2, c0s = (qa0 & 3) ^ ((r0s >> 1) & 3);
    int r1s = qa1 >> 2, c1s = (qa1 & 3) ^ ((r1s >> 1) & 3);
    int ar0 = m0 + r0s; if (ar0 > Mm - 1) ar0 = Mm - 1;
    int ar1 = m0 + r1s; if (ar1 > Mm - 1) ar1 = Mm - 1;
    int br0 = n0 + r0s; if (br0 > Nn - 1) br0 = Nn - 1;
    int br1 = n0 + r1s; if (br1 > Nn - 1) br1 = Nn - 1;
    const us* pa0 = A + (ll)ar0 * lda + c0s * 8;
    const us* pa1 = A + (ll)ar1 * lda + c1s * 8;
    const us* pb0 = Bt + (ll)br0 * ldb + c0s * 8;
    const us* pb1 = Bt + (ll)br1 * ldb + c1s * 8;
    int la0o = q0 * 8, la1o = (q0 + 64) * 8;

    int l15 = lane & 15, l4 = lane >> 4;
    int aoff[4], boff[4];
#pragma unroll
    for (int f = 0; f < 4; f++) {
        int row = wr * 64 + f * 16 + l15;
        aoff[f] = row * 32 + ((l4 ^ ((row >> 1) & 3)) << 3);
        int col = wc * 64 + f * 16 + l15;
        boff[f] = col * 32 + ((l4 ^ ((col >> 1) & 3)) << 3);
    }

    f32x4 acc[4][4];
#pragma unroll
    for (int i = 0; i < 4; i++)
#pragma unroll
        for (int j = 0; j < 4; j++) acc[i][j] = (f32x4){0.f, 0.f, 0.f, 0.f};

    auto stage = [&](int buf, int kt) {
        int k0 = kt << 5;
        gload16(pa0 + k0, &As[buf][la0o]);
        gload16(pa1 + k0, &As[buf][la1o]);
        gload16(pb0 + k0, &Bs[buf][la0o]);
        gload16(pb1 + k0, &Bs[buf][la1o]);
    };

    stage(0, 0);
    for (int kt = 0; kt < nkt; ++kt) {
        int cur = kt & 1;
        if (kt + 1 < nkt) {
            stage(cur ^ 1, kt + 1);
            asm volatile("s_waitcnt vmcnt(4)" ::: "memory");
        } else {
            asm volatile("s_waitcnt vmcnt(0)" ::: "memory");
        }
        __builtin_amdgcn_s_barrier();
        asm volatile("" ::: "memory");
        bf16x8 af[4], bfr[4];
#pragma unroll
        for (int f = 0; f < 4; f++) af[f] = *(const bf16x8*)&As[cur][aoff[f]];
#pragma unroll
        for (int f = 0; f < 4; f++) bfr[f] = *(const bf16x8*)&Bs[cur][boff[f]];
#pragma unroll
        for (int i = 0; i < 4; i++)
#pragma unroll
            for (int j = 0; j < 4; j++)
                acc[i][j] = __builtin_amdgcn_mfma_f32_16x16x32_bf16(af[i], bfr[j], acc[i][j], 0, 0, 0);
        asm volatile("" ::: "memory");
        __builtin_amdgcn_s_barrier();
        asm volatile("" ::: "memory");
    }

#pragma unroll
    for (int fm = 0; fm < 4; fm++) {
        int rb = m0 + wr * 64 + fm * 16 + l4 * 4;
#pragma unroll
        for (int fn = 0; fn < 4; fn++) {
            int c = n0 + wc * 64 + fn * 16 + l15;
            if (c >= Nstore) continue;
#pragma unroll
            for (int i = 0; i < 4; i++) {
                int r = rb + i - rSub;
                if (r < 0 || r >= Mstore) continue;
                float v = acc[fm][fn][i];
                if (EPI == 3) {
                    int part = c >> 9, hh = (c >> 6) & 7, dd = c & 63;
                    float o = (part == 0) ? v * 0.125f : v;
                    C2[((ll)(part * 8 + hh) * NPAD + r) * 64 + dd] = f2b(o);
                } else if (EPI == 10) {
                    C2[(ll)r * ldc + c] = f2b(v + bias[c]);
                } else if (EPI == 12) {
                    C2[(ll)r * ldc + c] = f2b(v + bias[c] + addp[(ll)r * ldadd + c]);
                }
            }
        }
    }
}

// ---------------------------------------------------------------------------
// mega1 (512 thr, 48KB LDS):
//   [0,16):        pinv, 2 WG/head (one per 128-row half), cross-block sync
//                  via device atomics (blocks 0-15 co-resident: first of 18K).
//   [16,488):      attn3, 1 chunk/block, waves 0-3 active.
//   [488,1432):    VAL = dense @ wv_w + b -> VALB bf16 (256x128, 16 MFMA/step).
//   [1432,3320):   attn1 softmax: P1[h][r][256] = softmax(Q@KL^T), 16 rows/wave.
//   [3320,18320):  depthwise conv residual -> ATTP bf16 (16 rows/block).
__global__ __launch_bounds__(512)
void mega1(const us* __restrict__ XN, us* __restrict__ ZN, us* __restrict__ ZT,
           us* __restrict__ ZN2, us* __restrict__ ZT2,
           us* __restrict__ Y, us* __restrict__ W1T, us* __restrict__ W2T,
           us* __restrict__ W3T,
           const us* __restrict__ QLB, const us* __restrict__ Kh,
           const us* __restrict__ VT, us* __restrict__ KVPb, float* __restrict__ ZP,
           const us* __restrict__ Vh, const float* __restrict__ cw,
           us* __restrict__ ATTP,
           const us* __restrict__ DENSEP, const us* __restrict__ WVT,
           const float* __restrict__ wvb, us* __restrict__ VALB,
           const us* __restrict__ Qh, const us* __restrict__ KLB,
           us* __restrict__ P1, int* __restrict__ FLAGS)
{
    __shared__ us LDSu[24576];   // 48 KB
    int b = blockIdx.x;
    int tid = threadIdx.x, w = tid >> 6, lane = tid & 63;
    int l15 = lane & 15, l4 = lane >> 4;

    if (b < 16) {
        // ------------- pinv role: 2 blocks/head, half hf each -------------
        __builtin_amdgcn_s_setprio(1);
        int head = b & 7, hf = b >> 3;
        ll hb = (ll)head << 16;
        int* flag = FLAGS + head * 16;
        int syncno = 0;
        int wr = w >> 2, wc = w & 3;            // 2x4 waves over 128x256 half
        int sra = tid >> 2, sca = ((tid & 3) ^ ((sra >> 1) & 3)) * 8;
        int q1 = tid + 512;
        int srb1 = q1 >> 2, scb1 = ((q1 & 3) ^ ((srb1 >> 1) & 3)) * 8;
        int aoff[4], boff[4];
#pragma unroll
        for (int f = 0; f < 4; f++) {
            int row = wr * 64 + f * 16 + l15;
            aoff[f] = row * 32 + ((l4 ^ ((row >> 1) & 3)) << 3);
            int col = wc * 64 + f * 16 + l15;
            boff[f] = 4096 + col * 32 + ((l4 ^ ((col >> 1) & 3)) << 3);
        }
        f32x4 acc[4][4];
        auto gemmS = [&](const us* Ah, const us* Bt) {   // Ah = half's first row
#pragma unroll
            for (int i = 0; i < 4; i++)
#pragma unroll
                for (int j = 0; j < 4; j++) acc[i][j] = (f32x4){0.f, 0.f, 0.f, 0.f};
            const us* pa  = Ah + (ll)sra * 256 + sca;
            const us* pb0 = Bt + (ll)sra * 256 + sca;
            const us* pb1 = Bt + (ll)srb1 * 256 + scb1;
            auto stg = [&](int buf, int kt) {
                int k0 = kt << 5;
                gload16(pa + k0, &LDSu[buf + tid * 8]);
                gload16(pb0 + k0, &LDSu[buf + 4096 + tid * 8]);
                gload16(pb1 + k0, &LDSu[buf + 8192 + tid * 8]);
            };
            stg(0, 0);
            for (int kt = 0; kt < 8; ++kt) {
                int buf = (kt & 1) * 12288;
                if (kt < 7) {
                    stg(buf ^ 12288, kt + 1);
                    asm volatile("s_waitcnt vmcnt(3)" ::: "memory");
                } else {
                    asm volatile("s_waitcnt vmcnt(0)" ::: "memory");
                }
                __builtin_amdgcn_s_barrier();
                asm volatile("" ::: "memory");
                bf16x8 af[4], bfr[4];
#pragma unroll
                for (int f = 0; f < 4; f++) af[f] = *(const bf16x8*)&LDSu[buf + aoff[f]];
#pragma unroll
                for (int f = 0; f < 4; f++) bfr[f] = *(const bf16x8*)&LDSu[buf + boff[f]];
#pragma unroll
                for (int i = 0; i < 4; i++)
#pragma unroll
                    for (int j = 0; j < 4; j++)
                        acc[i][j] = __builtin_amdgcn_mfma_f32_16x16x32_bf16(af[i], bfr[j], acc[i][j], 0, 0, 0);
                asm volatile("" ::: "memory");
                __builtin_amdgcn_s_barrier();
                asm volatile("" ::: "memory");
            }
        };
        // cross-block pair barrier: release stores, arrive, spin, acquire
        auto gsync = [&]() {
            __syncthreads();
            ++syncno;
            if (tid == 0) {
                __threadfence();
                atomicAdd(flag, 1);
                while (atomicAdd(flag, 0) < 2 * syncno)
                    __builtin_amdgcn_s_sleep(8);
                __threadfence();
            }
            __syncthreads();
        };

        us* znc = ZN; us* ztc = ZT; us* znn = ZN2; us* ztn = ZT2;
        for (int it = 0; it < NIT; ++it) {
            // S_A: Y = X@Z ; W1T = (7I - Y)^T   (own half rows / columns)
            gemmS(XN + hb + hf * 32768, ztc + hb);
#pragma unroll
            for (int fm = 0; fm < 4; fm++) {
                int rb = hf * 128 + wr * 64 + fm * 16 + l4 * 4;
#pragma unroll
                for (int fn = 0; fn < 4; fn++) {
                    int c = wc * 64 + fn * 16 + l15;
                    ushort4 u;
#pragma unroll
                    for (int i = 0; i < 4; i++) {
                        float v = acc[fm][fn][i];
                        Y[hb + (ll)(rb + i) * 256 + c] = f2b(v);
                        ((us*)&u)[i] = f2b(((rb + i == c) ? 7.0f : 0.0f) - v);
                    }
                    *(ushort4*)&W1T[hb + (ll)c * 256 + rb] = u;
                }
            }
            gsync();
            // S_B: W2T = (15I - Y@W1)^T
            gemmS(Y + hb + hf * 32768, W1T + hb);
#pragma unroll
            for (int fm = 0; fm < 4; fm++) {
                int rb = hf * 128 + wr * 64 + fm * 16 + l4 * 4;
#pragma unroll
                for (int fn = 0; fn < 4; fn++) {
                    int c = wc * 64 + fn * 16 + l15;
                    ushort4 u;
#pragma unroll
                    for (int i = 0; i < 4; i++)
                        ((us*)&u)[i] = f2b(((rb + i == c) ? 15.0f : 0.0f) - acc[fm][fn][i]);
                    *(ushort4*)&W2T[hb + (ll)c * 256 + rb] = u;
                }
            }
            gsync();
            // S_C: W3T = (13I - Y@W2)^T
            gemmS(Y + hb + hf * 32768, W2T + hb);
#pragma unroll
            for (int fm = 0; fm < 4; fm++) {
                int rb = hf * 128 + wr * 64 + fm * 16 + l4 * 4;
#pragma unroll
                for (int fn = 0; fn < 4; fn++) {
                    int c = wc * 64 + fn * 16 + l15;
                    ushort4 u;
#pragma unroll
                    for (int i = 0; i < 4; i++)
                        ((us*)&u)[i] = f2b(((rb + i == c) ? 13.0f : 0.0f) - acc[fm][fn][i]);
                    *(ushort4*)&W3T[hb + (ll)c * 256 + rb] = u;
                }
            }
            gsync();
            // S_D: Z' = 0.25 * Z@W3 (rows + transposed; T store dead on last it)
            gemmS(znc + hb + hf * 32768, W3T + hb);
#pragma unroll
            for (int fm = 0; fm < 4; fm++) {
                int rb = hf * 128 + wr * 64 + fm * 16 + l4 * 4;
#pragma unroll
                for (int fn = 0; fn < 4; fn++) {
                    int c = wc * 64 + fn * 16 + l15;
                    ushort4 u;
#pragma unroll
                    for (int i = 0; i < 4; i++) {
                        us q = f2b(0.25f * acc[fm][fn][i]);
                        znn[hb + (ll)(rb + i) * 256 + c] = q;
                        ((us*)&u)[i] = q;
                    }
                    if (it != NIT - 1)
                        *(ushort4*)&ztn[hb + (ll)c * 256 + rb] = u;
                }
            }
            if (it != NIT - 1) gsync();
            us* tp;
            tp = znc; znc = znn; znn = tp;
            tp = ztc; ztc = ztn; ztn = tp;
        }
    } else if (b < 488) {
        // ------------------------- attn3 role -------------------------
        if (w >= 4) return;
        int idx = b - 16;
        int h = idx & 7, chunk = idx >> 3;
        int c0 = chunk * 512;
        const us* QLh = QLB + (ll)h * 16384;
        const us* Khh = Kh + (ll)h * NPAD * 64;
        const us* VTh = VT + (ll)h * 64 * NPAD;
        us* P = &LDSu[w * 4096];

        bf16x8 aq[4][2];
#pragma unroll
        for (int fm = 0; fm < 4; fm++)
#pragma unroll
            for (int ks = 0; ks < 2; ks++)
                aq[fm][ks] = *(const bf16x8*)&QLh[(w * 64 + fm * 16 + l15) * 64 + l4 * 8 + ks * 32];

        f32x4 acc2[4][4];
        float zacc[4][4];
#pragma unroll
        for (int a = 0; a < 4; a++)
#pragma unroll
            for (int bb = 0; bb < 4; bb++) { acc2[a][bb] = (f32x4){0.f,0.f,0.f,0.f}; zacc[a][bb] = 0.f; }

        for (int sub = 0; sub < 8; ++sub) {
            int s0 = c0 + sub * 64;
            f32x4 s[4][4];
#pragma unroll
            for (int a = 0; a < 4; a++)
#pragma unroll
                for (int bb = 0; bb < 4; bb++) s[a][bb] = (f32x4){0.f,0.f,0.f,0.f};
#pragma unroll
            for (int ks = 0; ks < 2; ks++) {
                bf16x8 bk[4];
#pragma unroll
                for (int fn = 0; fn < 4; fn++)
                    bk[fn] = *(const bf16x8*)&Khh[(ll)(s0 + fn * 16 + l15) * 64 + l4 * 8 + ks * 32];
#pragma unroll
                for (int fm = 0; fm < 4; fm++)
#pragma unroll
                    for (int fn = 0; fn < 4; fn++)
                        s[fm][fn] = __builtin_amdgcn_mfma_f32_16x16x32_bf16(aq[fm][ks], bk[fn], s[fm][fn], 0, 0, 0);
            }
#pragma unroll
            for (int fm = 0; fm < 4; fm++)
#pragma unroll
                for (int i = 0; i < 4; i++) {
                    int row = fm * 16 + l4 * 4 + i;
#pragma unroll
                    for (int fn = 0; fn < 4; fn++) {
                        float e = __expf(s[fm][fn][i]);
                        zacc[fm][i] += e;
                        int col = fn * 16 + l15;
                        P[row * 64 + (((col >> 3) ^ (row & 7)) << 3) + (col & 7)] = f2b(e);
                    }
                }
#pragma unroll
            for (int ks = 0; ks < 2; ks++) {
                bf16x8 ap[4], bv[4];
#pragma unroll
                for (int fm = 0; fm < 4; fm++) {
                    int row = fm * 16 + l15;
                    int ch = (l4 + ks * 4) ^ (row & 7);
                    ap[fm] = *(const bf16x8*)&P[row * 64 + ch * 8];
                }
#pragma unroll
                for (int fn = 0; fn < 4; fn++)
                    bv[fn] = *(const bf16x8*)&VTh[(ll)(fn * 16 + l15) * NPAD + s0 + l4 * 8 + ks * 32];
#pragma unroll
                for (int fm = 0; fm < 4; fm++)
#pragma unroll
                    for (int fn = 0; fn < 4; fn++)
                        acc2[fm][fn] = __builtin_amdgcn_mfma_f32_16x16x32_bf16(ap[fm], bv[fn], acc2[fm][fn], 0, 0, 0);
            }
        }
        us* KP = KVPb + ((ll)h * NCHUNK + chunk) * 16384;
#pragma unroll
        for (int fm = 0; fm < 4; fm++)
#pragma unroll
            for (int fn = 0; fn < 4; fn++)
#pragma unroll
                for (int i = 0; i < 4; i++)
                    KP[(w * 64 + fm * 16 + l4 * 4 + i) * 64 + fn * 16 + l15] = f2b(acc2[fm][fn][i]);
#pragma unroll
        for (int fm = 0; fm < 4; fm++)
#pragma unroll
            for (int i = 0; i < 4; i++) {
                float zz = zacc[fm][i];
                zz += __shfl_xor(zz, 1, 64); zz += __shfl_xor(zz, 2, 64);
                zz += __shfl_xor(zz, 4, 64); zz += __shfl_xor(zz, 8, 64);
                if (l15 == 0)
                    ZP[((ll)h * NCHUNK + chunk) * 256 + w * 64 + fm * 16 + l4 * 4 + i] = zz;
            }
    } else if (b < 1432) {
        // --------------- VAL role: 256x128 tile, 16 MFMA/step ---------------
        int vb = b - 488;
        int bx = vb & 7, by = vb >> 3;          // by in [0,118)
        int m0 = by * 256, n0 = bx * 128;
        int wr = w >> 1, wc = w & 1;            // 4x2 waves, per-wave 64x64
        int qa0 = tid, qa1 = tid + 512;
        int ra0 = qa0 >> 2, ca0 = (qa0 & 3) ^ ((ra0 >> 1) & 3);
        int ra1 = qa1 >> 2, ca1 = (qa1 & 3) ^ ((ra1 >> 1) & 3);
        int ga0 = m0 + ra0; if (ga0 > NSEQ - 1) ga0 = NSEQ - 1;
        int ga1 = m0 + ra1; if (ga1 > NSEQ - 1) ga1 = NSEQ - 1;
        const us* pa0 = DENSEP + (ll)(ga0 + FPAD) * 1024 + ca0 * 8;
        const us* pa1 = DENSEP + (ll)(ga1 + FPAD) * 1024 + ca1 * 8;
        int rb_ = tid >> 2, cb_ = (tid & 3) ^ ((rb_ >> 1) & 3);
        const us* pb = WVT + (ll)(n0 + rb_) * 1024 + cb_ * 8;
        int aoff[4], boff[4];
#pragma unroll
        for (int f = 0; f < 4; f++) {
            int row = wr * 64 + f * 16 + l15;
            aoff[f] = row * 32 + ((l4 ^ ((row >> 1) & 3)) << 3);
            int col = wc * 64 + f * 16 + l15;
            boff[f] = 8192 + col * 32 + ((l4 ^ ((col >> 1) & 3)) << 3);
        }
        f32x4 acc[4][4];
#pragma unroll
        for (int i = 0; i < 4; i++)
#pragma unroll
            for (int j = 0; j < 4; j++) acc[i][j] = (f32x4){0.f, 0.f, 0.f, 0.f};

        auto stg = [&](int buf, int kt) {
            int k0 = kt << 5;
            gload16(pa0 + k0, &LDSu[buf + tid * 8]);
            gload16(pa1 + k0, &LDSu[buf + 4096 + tid * 8]);
            gload16(pb + k0, &LDSu[buf + 8192 + tid * 8]);
        };
        stg(0, 0);
        for (int kt = 0; kt < 32; ++kt) {
            int buf = (kt & 1) * 12288;
            if (kt < 31) {
                stg(buf ^ 12288, kt + 1);
                asm volatile("s_waitcnt vmcnt(3)" ::: "memory");
            } else {
                asm volatile("s_waitcnt vmcnt(0)" ::: "memory");
            }
            __builtin_amdgcn_s_barrier();
            asm volatile("" ::: "memory");
            bf16x8 af[4], bfr[4];
#pragma unroll
            for (int f = 0; f < 4; f++) af[f] = *(const bf16x8*)&LDSu[buf + aoff[f]];
#pragma unroll
            for (int f = 0; f < 4; f++) bfr[f] = *(const bf16x8*)&LDSu[buf + boff[f]];
#pragma unroll
            for (int i = 0; i < 4; i++)
#pragma unroll
                for (int j = 0; j < 4; j++)
                    acc[i][j] = __builtin_amdgcn_mfma_f32_16x16x32_bf16(af[i], bfr[j], acc[i][j], 0, 0, 0);
            asm volatile("" ::: "memory");
            __builtin_amdgcn_s_barrier();
            asm volatile("" ::: "memory");
        }
#pragma unroll
        for (int fm = 0; fm < 4; fm++) {
            int rb = m0 + wr * 64 + fm * 16 + l4 * 4;
#pragma unroll
            for (int fn = 0; fn < 4; fn++) {
                int c = n0 + wc * 64 + fn * 16 + l15;
                float bias = wvb[c];
#pragma unroll
                for (int i = 0; i < 4; i++) {
                    int r = rb + i;
                    if (r < NSEQ) VALB[(ll)r * 1024 + c] = f2b(acc[fm][fn][i] + bias);
                }
            }
        }
    } else if (b < 3320) {
        // ---------------- attn1 softmax role (pinv-independent) ----------------
        int idx = b - 1432;
        int h = idx & 7, rc = idx >> 3;          // rc 0..235
        int rb0 = rc * 128 + w * 16;             // this wave's 16 rows
        const us* Qhh = Qh + (ll)h * NPAD * 64;
        const us* KLh = KLB + (ll)h * 16384;
        us* P1h = P1 + (ll)h * NPAD * 256;

        int ra = rb0 + l15; if (ra > NSEQ - 1) ra = NSEQ - 1;
        bf16x8 aq0 = *(const bf16x8*)&Qhh[(ll)(ra + FPAD) * 64 + l4 * 8];
        bf16x8 aq1 = *(const bf16x8*)&Qhh[(ll)(ra + FPAD) * 64 + l4 * 8 + 32];

        f32x4 s[16];
#pragma unroll
        for (int fn = 0; fn < 16; fn++) s[fn] = (f32x4){0.f,0.f,0.f,0.f};
#pragma unroll
        for (int fn = 0; fn < 16; fn++) {
            bf16x8 bk0 = *(const bf16x8*)&KLh[(fn * 16 + l15) * 64 + l4 * 8];
            bf16x8 bk1 = *(const bf16x8*)&KLh[(fn * 16 + l15) * 64 + l4 * 8 + 32];
            s[fn] = __builtin_amdgcn_mfma_f32_16x16x32_bf16(aq0, bk0, s[fn], 0, 0, 0);
            s[fn] = __builtin_amdgcn_mfma_f32_16x16x32_bf16(aq1, bk1, s[fn], 0, 0, 0);
        }
#pragma unroll
        for (int i = 0; i < 4; i++) {
            float m = s[0][i];
#pragma unroll
            for (int fn = 1; fn < 16; fn++) m = fmaxf(m, s[fn][i]);
            m = fmaxf(m, __shfl_xor(m, 1, 64)); m = fmaxf(m, __shfl_xor(m, 2, 64));
            m = fmaxf(m, __shfl_xor(m, 4, 64)); m = fmaxf(m, __shfl_xor(m, 8, 64));
            float sum = 0.f;
#pragma unroll
            for (int fn = 0; fn < 16; fn++) {
                float e = __expf(s[fn][i] - m);
                s[fn][i] = e; sum += e;
            }
            sum += __shfl_xor(sum, 1, 64); sum += __shfl_xor(sum, 2, 64);
            sum += __shfl_xor(sum, 4, 64); sum += __shfl_xor(sum, 8, 64);
            float rinv = 1.0f / sum;
#pragma unroll
            for (int fn = 0; fn < 16; fn++) s[fn][i] *= rinv;
        }
#pragma unroll
        for (int i = 0; i < 4; i++) {
            int r = rb0 + l4 * 4 + i;
            if (r < NSEQ) {
#pragma unroll
                for (int fn = 0; fn < 16; fn++)
                    P1h[(ll)r * 256 + fn * 16 + l15] = f2b(s[fn][i]);
            }
        }
    } else {
        // ------------------------- conv role -------------------------
        int cc = b - 3320;
        int h = cc & 7, ig = cc >> 3;
        int i = ig * 16 + w * 2 + (lane >> 5);
        int d0 = (lane & 31) * 2;
        if (i >= NSEQ) return;
        const us* Vh2 = Vh + (ll)h * NPAD * 64;
        int n0 = FPAD + i - 16;
        float s0 = 0.f, s1 = 0.f;
#pragma unroll
        for (int kk = 0; kk < 33; ++kk) {
            int n = n0 + kk;
            if (n < NPAD) {
                float wgt = cw[h * 33 + kk];
                uint32 v2 = *(const uint32*)&Vh2[(ll)n * 64 + d0];
                s0 = fmaf(wgt, b2f((us)(v2 & 0xffff)), s0);
                s1 = fmaf(wgt, b2f((us)(v2 >> 16)), s1);
            }
        }
        uint32 o = (uint32)f2b(s0) | ((uint32)f2b(s1) << 16);
        *(uint32*)&ATTP[(ll)i * INNER + h * 64 + d0] = o;
    }
}

// ---------------------------------------------------------------------------
// fp32 GEMM (attn2). TB=1: C=A@B^T. EPI 0: C=alpha*acc.
#define BM 128
#define BN 64
#define BK 16
template<int TB, int EPI>
__global__ __launch_bounds__(256)
void gemm_k(const float* __restrict__ A, const float* __restrict__ B, float* __restrict__ C,
            int Mm, int Nn, int Kk, int lda, int ldb, int ldc,
            ll sA, ll sB, ll sC, float alpha, float diagv)
{
    __shared__ float As[BK][132];
    __shared__ float Bs[BK][68];
    int batch = blockIdx.z;
    A += (ll)batch * sA; B += (ll)batch * sB; C += (ll)batch * sC;
    int m0 = blockIdx.y * BM, n0 = blockIdx.x * BN;
    int tid = threadIdx.x, tx = tid & 15, ty = tid >> 4;
    int arow_t = tid >> 1, akh = (tid & 1) * 8;
    bool avalid = (m0 + arow_t < Mm);
    const float* Arow = A + (ll)(m0 + arow_t) * lda;
    float acc[8][4];
#pragma unroll
    for (int i = 0; i < 8; i++)
#pragma unroll
        for (int j = 0; j < 4; j++) acc[i][j] = 0.f;
    for (int kt = 0; kt < Kk / BK; ++kt) {
        int k0 = kt * BK;
        float4 av0 = make_float4(0, 0, 0, 0), av1 = av0;
        if (avalid) {
            av0 = *(const float4*)(Arow + k0 + akh);
            av1 = *(const float4*)(Arow + k0 + akh + 4);
        }
        float4 bv;
        if (TB == 0) bv = *(const float4*)(B + (ll)(k0 + (tid >> 4)) * ldb + n0 + (tid & 15) * 4);
        else         bv = *(const float4*)(B + (ll)(n0 + (tid >> 2)) * ldb + k0 + (tid & 3) * 4);
        __syncthreads();
        As[akh + 0][arow_t] = av0.x; As[akh + 1][arow_t] = av0.y;
        As[akh + 2][arow_t] = av0.z; As[akh + 3][arow_t] = av0.w;
        As[akh + 4][arow_t] = av1.x; As[akh + 5][arow_t] = av1.y;
        As[akh + 6][arow_t] = av1.z; As[akh + 7][arow_t] = av1.w;
        if (TB == 0) *(float4*)&Bs[tid >> 4][(tid & 15) * 4] = bv;
        else {
            int bk4 = (tid & 3) * 4, bn = tid >> 2;
            Bs[bk4 + 0][bn] = bv.x; Bs[bk4 + 1][bn] = bv.y;
            Bs[bk4 + 2][bn] = bv.z; Bs[bk4 + 3][bn] = bv.w;
        }
        __syncthreads();
#pragma unroll
        for (int kk = 0; kk < BK; kk++) {
            float ar[8], br[4];
            *(float4*)&ar[0] = *(const float4*)&As[kk][ty * 8];
            *(float4*)&ar[4] = *(const float4*)&As[kk][ty * 8 + 4];
            *(float4*)&br[0] = *(const float4*)&Bs[kk][tx * 4];
#pragma unroll
            for (int i = 0; i < 8; i++)
#pragma unroll
                for (int j = 0; j < 4; j++) acc[i][j] = fmaf(ar[i], br[j], acc[i][j]);
        }
    }
    int c0 = n0 + tx * 4;
#pragma unroll
    for (int i = 0; i < 8; i++) {
        int r = m0 + ty * 8 + i;
        if (r >= Mm) continue;
#pragma unroll
        for (int j = 0; j < 4; j++) {
            int c = c0 + j;
            if (c >= Nn) continue;
            if (EPI == 0) C[(ll)r * ldc + c] = alpha * acc[i][j];
        }
    }
}

__global__ void kv_reduce2(const us* __restrict__ KVPb, const float* __restrict__ ZP,
                           float* __restrict__ KV)
{
    int e = blockIdx.x * 256 + threadIdx.x;   // < 131072
    int h = e >> 14, r = (e >> 6) & 255;
    float s = 0.f, z = 0.f;
    for (int c = 0; c < NCHUNK; ++c) {
        s += b2f(KVPb[((ll)h * NCHUNK + c) * 16384 + (e & 16383)]);
        z += ZP[((ll)h * NCHUNK + c) * 256 + r];
    }
    KV[e] = s / z;
}

// ---------------------------------------------------------------------------
// pw_fused: PWT[h][c][r] = (pinv Z @ KV)[r][c].
__global__ __launch_bounds__(256)
void pw_fused(const us* __restrict__ ZNf, const float* __restrict__ KV,
              us* __restrict__ PWT)
{
    __shared__ us KT[64 * 264];
    int h = blockIdx.x;
    int tid = threadIdx.x, w = tid >> 6, lane = tid & 63;
    int l15 = lane & 15, l4 = lane >> 4;
    const float* KVh = KV + (ll)h * 16384;
#pragma unroll
    for (int i = 0; i < 64; ++i) {
        int idx = i * 256 + tid;
        int r = idx >> 6, c = idx & 63;
        KT[c * 264 + r] = f2b(KVh[idx]);
    }
    __syncthreads();
    const us* Zh = ZNf + ((ll)h << 16);
    f32x4 acc[4][4];
#pragma unroll
    for (int i = 0; i < 4; i++)
#pragma unroll
        for (int j = 0; j < 4; j++) acc[i][j] = (f32x4){0.f, 0.f, 0.f, 0.f};
    int rw = w * 64;
    for (int ks = 0; ks < 8; ++ks) {
        int k0 = ks * 32 + l4 * 8;
        bf16x8 af[4], bfr[4];
#pragma unroll
        for (int f = 0; f < 4; f++)
            af[f] = *(const bf16x8*)&Zh[(ll)(rw + f * 16 + l15) * 256 + k0];
#pragma unroll
        for (int f = 0; f < 4; f++)
            bfr[f] = *(const bf16x8*)&KT[(f * 16 + l15) * 264 + k0];
#pragma unroll
        for (int i = 0; i < 4; i++)
#pragma unroll
            for (int j = 0; j < 4; j++)
                acc[i][j] = __builtin_amdgcn_mfma_f32_16x16x32_bf16(af[i], bfr[j], acc[i][j], 0, 0, 0);
    }
    us* PWh = PWT + (ll)h * 16384;
#pragma unroll
    for (int fm = 0; fm < 4; fm++)
#pragma unroll
        for (int fn = 0; fn < 4; fn++)
#pragma unroll
            for (int i = 0; i < 4; i++) {
                int r = rw + fm * 16 + l4 * 4 + i;
                int c = fn * 16 + l15;
                PWh[c * 256 + r] = f2b(acc[fm][fn][i]);
            }
}

// ---------------------------------------------------------------------------
// attn1 PV: ATTP[r, h*64+d] += (P1[h] @ PW[h])  (conv residual in ATTP, RMW)
__global__ __launch_bounds__(256)
void attn1_pv(const us* __restrict__ P1, const us* __restrict__ PWT,
              us* __restrict__ ATTP)
{
    int h = blockIdx.y, r0 = blockIdx.x * 128;
    int w = threadIdx.x >> 6, lane = threadIdx.x & 63;
    int l15 = lane & 15, l4 = lane >> 4;
    const us* P1h = P1 + (ll)h * NPAD * 256;
    const us* PWh = PWT + (ll)h * 16384;

    int ra[2];
#pragma unroll
    for (int fm = 0; fm < 2; fm++) {
        int r = r0 + w * 32 + fm * 16 + l15;
        ra[fm] = (r > NSEQ - 1) ? (NSEQ - 1) : r;
    }
    f32x4 acc[2][4];
#pragma unroll
    for (int a = 0; a < 2; a++)
#pragma unroll
        for (int bq = 0; bq < 4; bq++) acc[a][bq] = (f32x4){0.f,0.f,0.f,0.f};

#pragma unroll
    for (int ks = 0; ks < 8; ++ks) {
        bf16x8 ap[2];
#pragma unroll
        for (int fm = 0; fm < 2; fm++)
            ap[fm] = *(const bf16x8*)&P1h[(ll)ra[fm] * 256 + ks * 32 + l4 * 8];
#pragma unroll
        for (int fn = 0; fn < 4; fn++) {
            bf16x8 bp = *(const bf16x8*)&PWh[(fn * 16 + l15) * 256 + ks * 32 + l4 * 8];
            acc[0][fn] = __builtin_amdgcn_mfma_f32_16x16x32_bf16(ap[0], bp, acc[0][fn], 0, 0, 0);
            acc[1][fn] = __builtin_amdgcn_mfma_f32_16x16x32_bf16(ap[1], bp, acc[1][fn], 0, 0, 0);
        }
    }
#pragma unroll
    for (int fm = 0; fm < 2; fm++)
#pragma unroll
        for (int fn = 0; fn < 4; fn++)
#pragma unroll
            for (int i = 0; i < 4; i++) {
                int r = r0 + w * 32 + fm * 16 + l4 * 4 + i;
                if (r < NSEQ) {
                    ll idx = (ll)r * 512 + h * 64 + fn * 16 + l15;
                    float a = acc[fm][fn][i] + b2f(ATTP[idx]);
                    ATTP[idx] = f2b(a);
                }
            }
}

// ---------------------------------------------------------------------------
__global__ void trans_f2b(const float* __restrict__ in, us* __restrict__ out,
                          int R, int Cc, ll sI, ll sO)
{
    __shared__ float tile[32][33];
    const float* inp = in + (ll)blockIdx.z * sI;
    us* outp = out + (ll)blockIdx.z * sO;
    int r0 = blockIdx.y * 32, c0 = blockIdx.x * 32;
    int tx = threadIdx.x & 31, ty = threadIdx.x >> 5;
#pragma unroll
    for (int i = 0; i < 4; i++) {
        int r = r0 + ty + i * 8, c = c0 + tx;
        tile[ty + i * 8][tx] = (r < R && c < Cc) ? inp[(ll)r * Cc + c] : 0.f;
    }
    __syncthreads();
#pragma unroll
    for (int i = 0; i < 4; i++) {
        int c = c0 + ty + i * 8, r = r0 + tx;
        if (c < Cc && r < R) outp[(ll)c * R + r] = f2b(tile[tx][ty + i * 8]);
    }
}

__global__ void trans_b2b(const us* __restrict__ in, us* __restrict__ out,
                          int R, int Cc, ll sI, ll sO)
{
    __shared__ us tile[32][34];
    const us* inp = in + (ll)blockIdx.z * sI;
    us* outp = out + (ll)blockIdx.z * sO;
    int r0 = blockIdx.y * 32, c0 = blockIdx.x * 32;
    int tx = threadIdx.x & 31, ty = threadIdx.x >> 5;
#pragma unroll
    for (int i = 0; i < 4; i++) {
        int r = r0 + ty + i * 8, c = c0 + tx;
        tile[ty + i * 8][tx] = (r < R && c < Cc) ? inp[(ll)r * Cc + c] : (us)0;
    }
    __syncthreads();
#pragma unroll
    for (int i = 0; i < 4; i++) {
        int c = c0 + ty + i * 8, r = r0 + tx;
        if (c < Cc && r < R) outp[(ll)c * R + r] = tile[tx][ty + i * 8];
    }
}

__global__ void dense_pad_b(const float* __restrict__ x, us* __restrict__ o)
{
    ll e4 = ((ll)blockIdx.x * 256 + threadIdx.x) * 4;
    int r = (int)(e4 >> 10), c = (int)(e4 & 1023);
    ushort4 u;
    if (r < FPAD) { u.x = u.y = u.z = u.w = 0; }
    else {
        float4 v = *(const float4*)&x[(ll)(r - FPAD) * 1024 + c];
        u.x = f2b(v.x); u.y = f2b(v.y); u.z = f2b(v.z); u.w = f2b(v.w);
    }
    *(ushort4*)&o[e4] = u;
}

__global__ void concat_bias(const float* __restrict__ a, const float* __restrict__ b,
                            float* __restrict__ o)
{
    int t = threadIdx.x;
    o[t] = a[t]; o[256 + t] = b[t];
}

__global__ void landmark_mean_b(const us* __restrict__ src, float* __restrict__ dst,
                                us* __restrict__ dstb)
{
    int b = blockIdx.x;
    int h = b >> 8, jm = b & 255;
    int d = threadIdx.x;
    const us* p = src + ((ll)h * NPAD + (ll)jm * LCHUNK) * DHEAD + d;
    float s = 0.f;
    for (int jl = 0; jl < LCHUNK; ++jl) s += b2f(p[jl * DHEAD]);
    float v = s * (1.0f / LCHUNK);
    dst[((h << 8) + jm) * DHEAD + d] = v;
    dstb[((h << 8) + jm) * DHEAD + d] = f2b(v);
}

__global__ void rowsoftmax256(float* __restrict__ X)
{
    __shared__ float red[256];
    float* p = X + (ll)blockIdx.x * 256;
    int t = threadIdx.x;
    float v = p[t];
    red[t] = v; __syncthreads();
    for (int s = 128; s > 0; s >>= 1) { if (t < s) red[t] = fmaxf(red[t], red[t + s]); __syncthreads(); }
    float m = red[0]; __syncthreads();
    float e = expf(v - m);
    red[t] = e; __syncthreads();
    for (int s = 128; s > 0; s >>= 1) { if (t < s) red[t] += red[t + s]; __syncthreads(); }
    p[t] = e / red[0];
}

__global__ void colrow_max(const float* __restrict__ A2, float* __restrict__ hm)
{
    __shared__ float red[256];
    int h = blockIdx.x, t = threadIdx.x;
    const float* X = A2 + (ll)h * LM * LM;
    float cs = 0.f;
    for (int i = 0; i < LM; ++i) cs += X[i * LM + t];
    red[t] = cs; __syncthreads();
    for (int s = 128; s > 0; s >>= 1) { if (t < s) red[t] = fmaxf(red[t], red[t + s]); __syncthreads(); }
    if (t == 0) hm[h] = red[0];
    __syncthreads();
    float rs = 0.f;
    const float* Xr = X + (ll)t * LM;
    for (int j = 0; j < LM; ++j) rs += Xr[j];
    red[t] = rs; __syncthreads();
    for (int s = 128; s > 0; s >>= 1) { if (t < s) red[t] = fmaxf(red[t], red[t + s]); __syncthreads(); }
    if (t == 0) hm[8 + h] = red[0];
}

__global__ void denom_fin(const float* __restrict__ hm, float* __restrict__ scal)
{
    float cm = hm[0], rm = hm[8];
    for (int h = 1; h < 8; ++h) { cm = fmaxf(cm, hm[h]); rm = fmaxf(rm, hm[8 + h]); }
    scal[0] = 1.0f / (cm * rm);
}

__global__ void pinv_init(const float* __restrict__ A2, const float* __restrict__ scal,
                          us* __restrict__ XN, us* __restrict__ ZN, us* __restrict__ ZT)
{
    ll e = (ll)blockIdx.x * 256 + threadIdx.x;
    int h = (int)(e >> 16), r = (int)(e >> 8) & 255, c = (int)e & 255;
    float v = A2[e];
    XN[e] = f2b(v);
    float vs = v * scal[0];
    ZT[e] = f2b(vs);
    ZN[((ll)h << 16) + ((ll)c << 8) + r] = f2b(vs);
}

__global__ void zero_f32(float* __restrict__ p, int n)
{
    int i = blockIdx.x * 256 + threadIdx.x;
    if (i < n) p[i] = 0.f;
}

__global__ void edge_scores_b(const int* __restrict__ ei, const float* __restrict__ adj,
                              const us* __restrict__ qk2, float* __restrict__ Araw, int E)
{
    int gw = (blockIdx.x * 256 + threadIdx.x) >> 6;
    int lane = threadIdx.x & 63;
    if (gw >= E) return;
    int src = ei[gw], dst = ei[E + gw];
    const uint32* qp = (const uint32*)(qk2 + (ll)src * 512);
    const uint32* kp = (const uint32*)(qk2 + (ll)dst * 512 + 256);
    float acc = 0.f;
#pragma unroll
    for (int t = 0; t < 2; t++) {
        uint32 qu = qp[lane + t * 64], ku = kp[lane + t * 64];
        acc += b2f((us)(qu & 0xffff)) * b2f((us)(ku & 0xffff));
        acc += b2f((us)(qu >> 16)) * b2f((us)(ku >> 16));
    }
#pragma unroll
    for (int m = 32; m >= 1; m >>= 1) acc += __shfl_xor(acc, m, 64);
    if (lane == 0) atomicAdd(Araw + src, acc * adj[gw] * 0.0625f);
}

__global__ void softmax30k_stats(const float* __restrict__ A, float* __restrict__ scal)
{
    __shared__ float red[1024];
    int t = threadIdx.x;
    float m = -3.0e38f;
    for (int i = t; i < NSEQ; i += 1024) m = fmaxf(m, A[i]);
    red[t] = m; __syncthreads();
    for (int s = 512; s > 0; s >>= 1) { if (t < s) red[t] = fmaxf(red[t], red[t + s]); __syncthreads(); }
    m = red[0]; __syncthreads();
    float sum = 0.f;
    for (int i = t; i < NSEQ; i += 1024) sum += expf(A[i] - m);
    red[t] = sum; __syncthreads();
    for (int s = 512; s > 0; s >>= 1) { if (t < s) red[t] += red[t + s]; __syncthreads(); }
    if (t == 0) { scal[1] = m; scal[2] = red[0]; }
}

// xo = gate(alpha(Araw)*val, enc); alpha computed inline (one row per block)
__global__ void gate_kernel(const float* __restrict__ Araw, const float* __restrict__ scal,
                            const us* __restrict__ VALB, const us* __restrict__ ENCB,
                            float* __restrict__ OUT)
{
    ll e4 = ((ll)blockIdx.x * 256 + threadIdx.x) * 4;
    int i = (int)(e4 >> 10);
    float a = __expf(Araw[i] - scal[1]) / scal[2];
    ushort4 vv = *(const ushort4*)&VALB[e4];
    ushort4 ee = *(const ushort4*)&ENCB[e4];
    float4 o;
    float* op = &o.x;
    const us* vp = (const us*)&vv;
    const us* ep = (const us*)&ee;
#pragma unroll
    for (int j = 0; j < 4; j++) {
        float xl = a * b2f(vp[j]);
        float sg = 1.0f / (1.0f + __expf(xl));
        float sw = sg * sg;
        op[j] = xl * 2.0f * sw + 2.0f * b2f(ep[j]) * (1.0f - sw);
    }
    *(float4*)&OUT[e4] = o;
}

// ---------------------------------------------------------------------------
extern "C" void kernel_launch(void* const* d_in, const int* in_sizes, int n_in,
                              void* d_out, int out_size, void* d_ws, size_t ws_size,
                              hipStream_t stream)
{
    const float* dense  = (const float*)d_in[0];
    const int*   ei     = (const int*)d_in[1];
    const float* adj    = (const float*)d_in[2];
    const float* qkv_w  = (const float*)d_in[3];
    const float* out_w  = (const float*)d_in[4];
    const float* out_b  = (const float*)d_in[5];
    const float* conv_w = (const float*)d_in[6];
    const float* wq_w   = (const float*)d_in[7];
    const float* wq_b   = (const float*)d_in[8];
    const float* wk_w   = (const float*)d_in[9];
    const float* wk_b   = (const float*)d_in[10];
    const float* wv_w   = (const float*)d_in[11];
    const float* wv_b   = (const float*)d_in[12];
    int E = in_sizes[2];

    char* w = (char*)d_ws;
    auto alloc = [&](ll bytes) { char* p = w; w += (bytes + 255) & ~(ll)255; return p; };

    us*    DENSEP = (us*)alloc((ll)NPAD * 1024 * 2);
    us*    QKVH   = (us*)alloc((ll)3 * 8 * NPAD * 64 * 2);
    us*    ENCB   = QKVH;                         // alias: Qh+Kh dead before out-proj writes ENCB
    us*    Qh = QKVH, *Kh = QKVH + (ll)8 * NPAD * 64, *Vh = QKVH + (ll)16 * NPAD * 64;
    us*    VT     = (us*)alloc((ll)8 * 64 * NPAD * 2);
    us*    QKVWT  = (us*)alloc((ll)1536 * 1024 * 2);
    us*    OUTWT  = (us*)alloc((ll)1024 * 512 * 2);
    us*    WQKT   = (us*)alloc((ll)512 * 1024 * 2);
    us*    WVT    = (us*)alloc((ll)1024 * 1024 * 2);
    float* WQKB   = (float*)alloc(512 * 4);
    float* QL     = (float*)alloc((ll)8 * 256 * 64 * 4);
    float* KL     = (float*)alloc((ll)8 * 256 * 64 * 4);
    us*    QLB    = (us*)alloc((ll)8 * 256 * 64 * 2);
    us*    KLB    = (us*)alloc((ll)8 * 256 * 64 * 2);
    float* A2     = (float*)alloc((ll)8 * 65536 * 4);
    us*    XN     = (us*)alloc((ll)8 * 65536 * 2);
    us*    ZN     = (us*)alloc((ll)8 * 65536 * 2);
    us*    ZT     = (us*)alloc((ll)8 * 65536 * 2);
    us*    ZN2    = (us*)alloc((ll)8 * 65536 * 2);
    us*    ZT2    = (us*)alloc((ll)8 * 65536 * 2);
    us*    Ybuf   = (us*)alloc((ll)8 * 65536 * 2);
    us*    W1T    = (us*)alloc((ll)8 * 65536 * 2);
    us*    W2T    = (us*)alloc((ll)8 * 65536 * 2);
    us*    W3T    = (us*)alloc((ll)8 * 65536 * 2);
    us*    KVPb   = (us*)alloc((ll)8 * NCHUNK * 16384 * 2);
    float* ZP     = (float*)alloc((ll)8 * NCHUNK * 256 * 4);
    float* KV     = (float*)alloc((ll)8 * 16384 * 4);
    us*    PWT    = (us*)alloc((ll)8 * 16384 * 2);
    float* HM     = (float*)alloc(64 * 4);
    float* SC     = (float*)alloc(64 * 4);
    int*   FLAGS  = (int*)alloc(8 * 16 * 4);      // pinv pair-barrier counters
    us*    ATTP   = (us*)alloc((ll)NSEQ * 512 * 2);
    us*    QK2B   = ATTP;                         // alias: ATTP dead after out-proj
    us*    VALB   = (us*)alloc((ll)NSEQ * 1024 * 2);
    us*    P1     = (us*)alloc((ll)8 * NPAD * 256 * 2);   // attn1 softmax probs

    float* OUT  = (float*)d_out;
    float* ARAW = OUT + (ll)NSEQ * DMODEL;

    // ---- prep
    trans_f2b<<<dim3(48, 32, 1), 256, 0, stream>>>(qkv_w, QKVWT, 1024, 1536, 0, 0);
    trans_f2b<<<dim3(32, 16, 1), 256, 0, stream>>>(out_w, OUTWT, 512, 1024, 0, 0);
    trans_f2b<<<dim3(8, 32, 1), 256, 0, stream>>>(wq_w, WQKT, 1024, 256, 0, 0);
    trans_f2b<<<dim3(8, 32, 1), 256, 0, stream>>>(wk_w, WQKT + (ll)256 * 1024, 1024, 256, 0, 0);
    trans_f2b<<<dim3(32, 32, 1), 256, 0, stream>>>(wv_w, WVT, 1024, 1024, 0, 0);
    concat_bias<<<1, 256, 0, stream>>>(wq_b, wk_b, WQKB);
    dense_pad_b<<<NPAD, 256, 0, stream>>>(dense, DENSEP);

    // ---- QKV projection -> per-head bf16 Q,K,V (q pre-scaled by 1/8)
    bgemm<3><<<dim3(12, 236, 1), 256, 0, stream>>>(DENSEP, QKVWT, nullptr, QKVH,
        nullptr, nullptr, NPAD, 1536, 1024, 1024, 1024, 0, 0, NPAD, 1536, 0);

    // ---- landmarks (fp32 + bf16 in one pass)
    landmark_mean_b<<<2048, 64, 0, stream>>>(Qh, QL, QLB);
    landmark_mean_b<<<2048, 64, 0, stream>>>(Kh, KL, KLB);

    // ---- attn2 (fp32) + denom
    gemm_k<1, 0><<<dim3(4, 2, 8), 256, 0, stream>>>(QL, KL, A2, LM, LM, DHEAD,
        DHEAD, DHEAD, LM, LM * DHEAD, LM * DHEAD, LM * LM, 1.f, 0.f);
    rowsoftmax256<<<2048, 256, 0, stream>>>(A2);
    colrow_max<<<8, 256, 0, stream>>>(A2, HM);
    denom_fin<<<1, 1, 0, stream>>>(HM, SC);
    pinv_init<<<2048, 256, 0, stream>>>(A2, SC, XN, ZN, ZT);
    zero_f32<<<1, 128, 0, stream>>>((float*)FLAGS, 128);

    // ---- V transpose (attn3's B operand) must precede mega
    trans_b2b<<<dim3(2, 944, 8), 256, 0, stream>>>(Vh, VT, NPAD, 64, (ll)NPAD * 64, (ll)64 * NPAD);

    // ---- MEGA: pinv(16, 2/head) || attn3(472) || VAL(944) || P1(1888) || conv(15000)
    mega1<<<18320, 512, 0, stream>>>(XN, ZN, ZT, ZN2, ZT2, Ybuf, W1T, W2T, W3T,
                                     QLB, Kh, VT, KVPb, ZP, Vh, conv_w, ATTP,
                                     DENSEP, WVT, wv_b, VALB, Qh, KLB, P1, FLAGS);

    // ---- KV reduce -> PWT (fused; NIT=4 even swaps => pinv result in ZN)
    kv_reduce2<<<512, 256, 0, stream>>>(KVPb, ZP, KV);
    pw_fused<<<8, 256, 0, stream>>>(ZN, KV, PWT);

    // ---- attn1 PV (P1 @ PW + conv residual already in ATTP)
    attn1_pv<<<dim3(235, 8), 256, 0, stream>>>(P1, PWT, ATTP);

    // ---- out projection + bias + dense residual -> ENCB bf16 only
    bgemm<12><<<dim3(8, 235, 1), 256, 0, stream>>>(ATTP, OUTWT, nullptr, ENCB,
        out_b, dense, NSEQ, 1024, 512, 512, 512, 1024, 1024, NSEQ, 1024, 0);

    // ---- merged q2|k2 projection (bf16 out, [row][512] layout)
    bgemm<10><<<dim3(4, 235, 1), 256, 0, stream>>>(ENCB, WQKT, nullptr, QK2B,
        WQKB, nullptr, NSEQ, 512, 1024, 1024, 1024, 512, 0, NSEQ, 512, 0);

    // ---- edges -> A_raw -> softmax stats (alpha folded into gate)
    zero_f32<<<(NSEQ + 255) / 256, 256, 0, stream>>>(ARAW, NSEQ);
    edge_scores_b<<<(E + 3) / 4, 256, 0, stream>>>(ei, adj, QK2B, ARAW, E);
    softmax30k_stats<<<1, 1024, 0, stream>>>(ARAW, SC);

    // ---- final gating (reads ARAW + VALB + ENCB, writes xo fp32)
    gate_kernel<<<30000, 256, 0, stream>>>(ARAW, SC, VALB, ENCB, OUT);
}

// Round 21
// 1209.301 us; speedup vs baseline: 1.0594x; 1.0594x over previous
//
#include <hip/hip_runtime.h>

#define NSEQ   30000
#define NPAD   30208
#define FPAD   208
#define DMODEL 1024
#define NHEAD  8
#define DHEAD  64
#define LM     256
#define LCHUNK 118
#define INNER  512
#define NCHUNK 59     // NPAD / 512
#define NIT    4      // Newton-Schulz iterations (E'≈0.75E³; eps4 ~1e-5 << bf16 noise)

typedef long long ll;
typedef unsigned short us;
typedef unsigned int uint32;
typedef __attribute__((ext_vector_type(8))) __bf16 bf16x8;
typedef __attribute__((ext_vector_type(4))) float f32x4;

__device__ __forceinline__ float b2f(us u) {
    union { unsigned int i; float f; } x; x.i = ((unsigned int)u) << 16; return x.f;
}
__device__ __forceinline__ us f2b(float f) {
    union { float f; unsigned int i; } x; x.f = f;
    unsigned int r = x.i + 0x7fffu + ((x.i >> 16) & 1u);
    return (us)(r >> 16);
}
__device__ __forceinline__ void gload16(const us* g, us* l) {
    __builtin_amdgcn_global_load_lds(
        (__attribute__((address_space(1))) void*)(const_cast<us*>(g)),
        (__attribute__((address_space(3))) void*)l, 16, 0, 0);
}

// ---------------------------------------------------------------------------
// bf16 MFMA GEMM, 256x128 tile, BK=32, 8 waves (4x2, per-wave 64x64 = 16
// MFMA/step), 2-phase dbuf + counted vmcnt(3) + XCD-bijective swizzle.
// EPI: 3 QKV scatter (q*0.125); 10 C2=bf16(acc+bias); 12 C2=bf16(acc+bias+addp)
// ---------------------------------------------------------------------------
template<int EPI>
__global__ __launch_bounds__(512)
void bgemm(const us* __restrict__ A, const us* __restrict__ Bt,
           float* __restrict__ C, us* __restrict__ C2,
           const float* __restrict__ bias, const float* __restrict__ addp,
           int Mm, int Nn, int Kk, int lda, int ldb, int ldc, int ldadd,
           int Mstore, int Nstore, int rSub)
{
    __shared__ us As[2][256 * 32];
    __shared__ us Bs[2][128 * 32];

    int nwg = gridDim.x * gridDim.y;
    int orig = blockIdx.y * gridDim.x + blockIdx.x;
    int qd = nwg >> 3, rm = nwg & 7;
    int xcd = orig & 7, off = orig >> 3;
    int swz = (xcd < rm ? xcd * (qd + 1) : rm * (qd + 1) + (xcd - rm) * qd) + off;
    int by = swz / gridDim.x, bx = swz - by * gridDim.x;
    int m0 = by * 256, n0 = bx * 128;

    int tid = threadIdx.x, w = tid >> 6, lane = tid & 63;
    int wr = w >> 1, wc = w & 1;
    int nkt = Kk >> 5;

    // A staging: 256x32 = 1024 slots of 8 elts, 2 per thread
    int qa0 = tid, qa1 = tid + 512;
    int ra0 = qa0 >> 2, ca0 = (qa0 & 3) ^ ((ra0 >> 1) & 3);
    int ra1 = qa1 >> 2, ca1 = (qa1 & 3) ^ ((ra1 >> 1) & 3);
    int ar0 = m0 + ra0; if (ar0 > Mm - 1) ar0 = Mm - 1;
    int ar1 = m0 + ra1; if (ar1 > Mm - 1) ar1 = Mm - 1;
    const us* pa0 = A + (ll)ar0 * lda + ca0 * 8;
    const us* pa1 = A + (ll)ar1 * lda + ca1 * 8;
    // B staging: 128x32 = 512 slots, 1 per thread
    int rb_ = tid >> 2, cb_ = (tid & 3) ^ ((rb_ >> 1) & 3);
    int br = n0 + rb_; if (br > Nn - 1) br = Nn - 1;
    const us* pb = Bt + (ll)br * ldb + cb_ * 8;

    int l15 = lane & 15, l4 = lane >> 4;
    int aoff[4], boff[4];
#pragma unroll
    for (int f = 0; f < 4; f++) {
        int row = wr * 64 + f * 16 + l15;
        aoff[f] = row * 32 + ((l4 ^ ((row >> 1) & 3)) << 3);
        int col = wc * 64 + f * 16 + l15;
        boff[f] = col * 32 + ((l4 ^ ((col >> 1) & 3)) << 3);
    }

    f32x4 acc[4][4];
#pragma unroll
    for (int i = 0; i < 4; i++)
#pragma unroll
        for (int j = 0; j < 4; j++) acc[i][j] = (f32x4){0.f, 0.f, 0.f, 0.f};

    auto stage = [&](int buf, int kt) {
        int k0 = kt << 5;
        gload16(pa0 + k0, &As[buf][tid * 8]);
        gload16(pa1 + k0, &As[buf][4096 + tid * 8]);
        gload16(pb + k0, &Bs[buf][tid * 8]);
    };

    stage(0, 0);
    for (int kt = 0; kt < nkt; ++kt) {
        int cur = kt & 1;
        if (kt + 1 < nkt) {
            stage(cur ^ 1, kt + 1);
            asm volatile("s_waitcnt vmcnt(3)" ::: "memory");
        } else {
            asm volatile("s_waitcnt vmcnt(0)" ::: "memory");
        }
        __builtin_amdgcn_s_barrier();
        asm volatile("" ::: "memory");
        bf16x8 af[4], bfr[4];
#pragma unroll
        for (int f = 0; f < 4; f++) af[f] = *(const bf16x8*)&As[cur][aoff[f]];
#pragma unroll
        for (int f = 0; f < 4; f++) bfr[f] = *(const bf16x8*)&Bs[cur][boff[f]];
#pragma unroll
        for (int i = 0; i < 4; i++)
#pragma unroll
            for (int j = 0; j < 4; j++)
                acc[i][j] = __builtin_amdgcn_mfma_f32_16x16x32_bf16(af[i], bfr[j], acc[i][j], 0, 0, 0);
        asm volatile("" ::: "memory");
        __builtin_amdgcn_s_barrier();
        asm volatile("" ::: "memory");
    }

#pragma unroll
    for (int fm = 0; fm < 4; fm++) {
        int rb = m0 + wr * 64 + fm * 16 + l4 * 4;
#pragma unroll
        for (int fn = 0; fn < 4; fn++) {
            int c = n0 + wc * 64 + fn * 16 + l15;
            if (c >= Nstore) continue;
#pragma unroll
            for (int i = 0; i < 4; i++) {
                int r = rb + i - rSub;
                if (r < 0 || r >= Mstore) continue;
                float v = acc[fm][fn][i];
                if (EPI == 3) {
                    int part = c >> 9, hh = (c >> 6) & 7, dd = c & 63;
                    float o = (part == 0) ? v * 0.125f : v;
                    C2[((ll)(part * 8 + hh) * NPAD + r) * 64 + dd] = f2b(o);
                } else if (EPI == 10) {
                    C2[(ll)r * ldc + c] = f2b(v + bias[c]);
                } else if (EPI == 12) {
                    C2[(ll)r * ldc + c] = f2b(v + bias[c] + addp[(ll)r * ldadd + c]);
                }
            }
        }
    }
}

// ---------------------------------------------------------------------------
// mega1 (512 thr, 48KB LDS):
//   [0,8):         pinv, 1 WG/head, 2 halves of 128x256/stage, dbuf vmcnt(3),
//                  setprio(1), syncthreads-only, NIT=4 cubic NS iterations.
//   [8,480):       attn3, 1 chunk/block, waves 0-3 active.
//   [480,1424):    VAL = dense @ wv_w + b -> VALB bf16 (256x128, 16 MFMA/step).
//   [1424,3312):   attn1 softmax: P1[h][r][256] = softmax(Q@KL^T), 16 rows/wave.
//   [3312,18312):  depthwise conv residual -> ATTP bf16 (16 rows/block).
__global__ __launch_bounds__(512)
void mega1(const us* __restrict__ XN, us* __restrict__ ZN, us* __restrict__ ZT,
           us* __restrict__ ZN2, us* __restrict__ ZT2,
           us* __restrict__ Y, us* __restrict__ W1T, us* __restrict__ W2T,
           us* __restrict__ W3T,
           const us* __restrict__ QLB, const us* __restrict__ Kh,
           const us* __restrict__ VT, us* __restrict__ KVPb, float* __restrict__ ZP,
           const us* __restrict__ Vh, const float* __restrict__ cw,
           us* __restrict__ ATTP,
           const us* __restrict__ DENSEP, const us* __restrict__ WVT,
           const float* __restrict__ wvb, us* __restrict__ VALB,
           const us* __restrict__ Qh, const us* __restrict__ KLB,
           us* __restrict__ P1)
{
    __shared__ us LDSu[24576];   // 48 KB
    int b = blockIdx.x;
    int tid = threadIdx.x, w = tid >> 6, lane = tid & 63;
    int l15 = lane & 15, l4 = lane >> 4;

    if (b < 8) {
        // ------------------------- pinv role -------------------------
        __builtin_amdgcn_s_setprio(1);
        ll hb = (ll)b << 16;
        int wr = w >> 2, wc = w & 3;            // 2x4 waves over 128x256 half
        int sra = tid >> 2, sca = ((tid & 3) ^ ((sra >> 1) & 3)) * 8;
        int q1 = tid + 512;
        int srb1 = q1 >> 2, scb1 = ((q1 & 3) ^ ((srb1 >> 1) & 3)) * 8;
        int aoff[4], boff[4];
#pragma unroll
        for (int f = 0; f < 4; f++) {
            int row = wr * 64 + f * 16 + l15;
            aoff[f] = row * 32 + ((l4 ^ ((row >> 1) & 3)) << 3);
            int col = wc * 64 + f * 16 + l15;
            boff[f] = 4096 + col * 32 + ((l4 ^ ((col >> 1) & 3)) << 3);
        }
        f32x4 acc[4][4];
        auto gemmS = [&](const us* Ah, const us* Bt) {   // Ah = half's first row
#pragma unroll
            for (int i = 0; i < 4; i++)
#pragma unroll
                for (int j = 0; j < 4; j++) acc[i][j] = (f32x4){0.f, 0.f, 0.f, 0.f};
            const us* pa  = Ah + (ll)sra * 256 + sca;
            const us* pb0 = Bt + (ll)sra * 256 + sca;
            const us* pb1 = Bt + (ll)srb1 * 256 + scb1;
            auto stg = [&](int buf, int kt) {
                int k0 = kt << 5;
                gload16(pa + k0, &LDSu[buf + tid * 8]);
                gload16(pb0 + k0, &LDSu[buf + 4096 + tid * 8]);
                gload16(pb1 + k0, &LDSu[buf + 8192 + tid * 8]);
            };
            stg(0, 0);
            for (int kt = 0; kt < 8; ++kt) {
                int buf = (kt & 1) * 12288;
                if (kt < 7) {
                    stg(buf ^ 12288, kt + 1);
                    asm volatile("s_waitcnt vmcnt(3)" ::: "memory");
                } else {
                    asm volatile("s_waitcnt vmcnt(0)" ::: "memory");
                }
                __builtin_amdgcn_s_barrier();
                asm volatile("" ::: "memory");
                bf16x8 af[4], bfr[4];
#pragma unroll
                for (int f = 0; f < 4; f++) af[f] = *(const bf16x8*)&LDSu[buf + aoff[f]];
#pragma unroll
                for (int f = 0; f < 4; f++) bfr[f] = *(const bf16x8*)&LDSu[buf + boff[f]];
#pragma unroll
                for (int i = 0; i < 4; i++)
#pragma unroll
                    for (int j = 0; j < 4; j++)
                        acc[i][j] = __builtin_amdgcn_mfma_f32_16x16x32_bf16(af[i], bfr[j], acc[i][j], 0, 0, 0);
                asm volatile("" ::: "memory");
                __builtin_amdgcn_s_barrier();
                asm volatile("" ::: "memory");
            }
        };

        us* znc = ZN; us* ztc = ZT; us* znn = ZN2; us* ztn = ZT2;
        for (int it = 0; it < NIT; ++it) {
            // S_A: Y = X@Z ; W1T = (7I - Y)^T
#pragma unroll
            for (int hf = 0; hf < 2; ++hf) {
                gemmS(XN + hb + hf * 32768, ztc + hb);
#pragma unroll
                for (int fm = 0; fm < 4; fm++) {
                    int rb = hf * 128 + wr * 64 + fm * 16 + l4 * 4;
#pragma unroll
                    for (int fn = 0; fn < 4; fn++) {
                        int c = wc * 64 + fn * 16 + l15;
                        ushort4 u;
#pragma unroll
                        for (int i = 0; i < 4; i++) {
                            float v = acc[fm][fn][i];
                            Y[hb + (ll)(rb + i) * 256 + c] = f2b(v);
                            ((us*)&u)[i] = f2b(((rb + i == c) ? 7.0f : 0.0f) - v);
                        }
                        *(ushort4*)&W1T[hb + (ll)c * 256 + rb] = u;
                    }
                }
            }
            __syncthreads();
            // S_B: W2T = (15I - Y@W1)^T
#pragma unroll
            for (int hf = 0; hf < 2; ++hf) {
                gemmS(Y + hb + hf * 32768, W1T + hb);
#pragma unroll
                for (int fm = 0; fm < 4; fm++) {
                    int rb = hf * 128 + wr * 64 + fm * 16 + l4 * 4;
#pragma unroll
                    for (int fn = 0; fn < 4; fn++) {
                        int c = wc * 64 + fn * 16 + l15;
                        ushort4 u;
#pragma unroll
                        for (int i = 0; i < 4; i++)
                            ((us*)&u)[i] = f2b(((rb + i == c) ? 15.0f : 0.0f) - acc[fm][fn][i]);
                        *(ushort4*)&W2T[hb + (ll)c * 256 + rb] = u;
                    }
                }
            }
            __syncthreads();
            // S_C: W3T = (13I - Y@W2)^T
#pragma unroll
            for (int hf = 0; hf < 2; ++hf) {
                gemmS(Y + hb + hf * 32768, W2T + hb);
#pragma unroll
                for (int fm = 0; fm < 4; fm++) {
                    int rb = hf * 128 + wr * 64 + fm * 16 + l4 * 4;
#pragma unroll
                    for (int fn = 0; fn < 4; fn++) {
                        int c = wc * 64 + fn * 16 + l15;
                        ushort4 u;
#pragma unroll
                        for (int i = 0; i < 4; i++)
                            ((us*)&u)[i] = f2b(((rb + i == c) ? 13.0f : 0.0f) - acc[fm][fn][i]);
                        *(ushort4*)&W3T[hb + (ll)c * 256 + rb] = u;
                    }
                }
            }
            __syncthreads();
            // S_D: Z' = 0.25 * Z@W3 (rows + transposed; T store dead on last it)
#pragma unroll
            for (int hf = 0; hf < 2; ++hf) {
                gemmS(znc + hb + hf * 32768, W3T + hb);
#pragma unroll
                for (int fm = 0; fm < 4; fm++) {
                    int rb = hf * 128 + wr * 64 + fm * 16 + l4 * 4;
#pragma unroll
                    for (int fn = 0; fn < 4; fn++) {
                        int c = wc * 64 + fn * 16 + l15;
                        ushort4 u;
#pragma unroll
                        for (int i = 0; i < 4; i++) {
                            us q = f2b(0.25f * acc[fm][fn][i]);
                            znn[hb + (ll)(rb + i) * 256 + c] = q;
                            ((us*)&u)[i] = q;
                        }
                        if (it != NIT - 1)
                            *(ushort4*)&ztn[hb + (ll)c * 256 + rb] = u;
                    }
                }
            }
            __syncthreads();
            us* tp;
            tp = znc; znc = znn; znn = tp;
            tp = ztc; ztc = ztn; ztn = tp;
        }
    } else if (b < 480) {
        // ------------------------- attn3 role -------------------------
        if (w >= 4) return;
        int idx = b - 8;
        int h = idx & 7, chunk = idx >> 3;
        int c0 = chunk * 512;
        const us* QLh = QLB + (ll)h * 16384;
        const us* Khh = Kh + (ll)h * NPAD * 64;
        const us* VTh = VT + (ll)h * 64 * NPAD;
        us* P = &LDSu[w * 4096];

        bf16x8 aq[4][2];
#pragma unroll
        for (int fm = 0; fm < 4; fm++)
#pragma unroll
            for (int ks = 0; ks < 2; ks++)
                aq[fm][ks] = *(const bf16x8*)&QLh[(w * 64 + fm * 16 + l15) * 64 + l4 * 8 + ks * 32];

        f32x4 acc2[4][4];
        float zacc[4][4];
#pragma unroll
        for (int a = 0; a < 4; a++)
#pragma unroll
            for (int bb = 0; bb < 4; bb++) { acc2[a][bb] = (f32x4){0.f,0.f,0.f,0.f}; zacc[a][bb] = 0.f; }

        for (int sub = 0; sub < 8; ++sub) {
            int s0 = c0 + sub * 64;
            f32x4 s[4][4];
#pragma unroll
            for (int a = 0; a < 4; a++)
#pragma unroll
                for (int bb = 0; bb < 4; bb++) s[a][bb] = (f32x4){0.f,0.f,0.f,0.f};
#pragma unroll
            for (int ks = 0; ks < 2; ks++) {
                bf16x8 bk[4];
#pragma unroll
                for (int fn = 0; fn < 4; fn++)
                    bk[fn] = *(const bf16x8*)&Khh[(ll)(s0 + fn * 16 + l15) * 64 + l4 * 8 + ks * 32];
#pragma unroll
                for (int fm = 0; fm < 4; fm++)
#pragma unroll
                    for (int fn = 0; fn < 4; fn++)
                        s[fm][fn] = __builtin_amdgcn_mfma_f32_16x16x32_bf16(aq[fm][ks], bk[fn], s[fm][fn], 0, 0, 0);
            }
#pragma unroll
            for (int fm = 0; fm < 4; fm++)
#pragma unroll
                for (int i = 0; i < 4; i++) {
                    int row = fm * 16 + l4 * 4 + i;
#pragma unroll
                    for (int fn = 0; fn < 4; fn++) {
                        float e = __expf(s[fm][fn][i]);
                        zacc[fm][i] += e;
                        int col = fn * 16 + l15;
                        P[row * 64 + (((col >> 3) ^ (row & 7)) << 3) + (col & 7)] = f2b(e);
                    }
                }
#pragma unroll
            for (int ks = 0; ks < 2; ks++) {
                bf16x8 ap[4], bv[4];
#pragma unroll
                for (int fm = 0; fm < 4; fm++) {
                    int row = fm * 16 + l15;
                    int ch = (l4 + ks * 4) ^ (row & 7);
                    ap[fm] = *(const bf16x8*)&P[row * 64 + ch * 8];
                }
#pragma unroll
                for (int fn = 0; fn < 4; fn++)
                    bv[fn] = *(const bf16x8*)&VTh[(ll)(fn * 16 + l15) * NPAD + s0 + l4 * 8 + ks * 32];
#pragma unroll
                for (int fm = 0; fm < 4; fm++)
#pragma unroll
                    for (int fn = 0; fn < 4; fn++)
                        acc2[fm][fn] = __builtin_amdgcn_mfma_f32_16x16x32_bf16(ap[fm], bv[fn], acc2[fm][fn], 0, 0, 0);
            }
        }
        us* KP = KVPb + ((ll)h * NCHUNK + chunk) * 16384;
#pragma unroll
        for (int fm = 0; fm < 4; fm++)
#pragma unroll
            for (int fn = 0; fn < 4; fn++)
#pragma unroll
                for (int i = 0; i < 4; i++)
                    KP[(w * 64 + fm * 16 + l4 * 4 + i) * 64 + fn * 16 + l15] = f2b(acc2[fm][fn][i]);
#pragma unroll
        for (int fm = 0; fm < 4; fm++)
#pragma unroll
            for (int i = 0; i < 4; i++) {
                float zz = zacc[fm][i];
                zz += __shfl_xor(zz, 1, 64); zz += __shfl_xor(zz, 2, 64);
                zz += __shfl_xor(zz, 4, 64); zz += __shfl_xor(zz, 8, 64);
                if (l15 == 0)
                    ZP[((ll)h * NCHUNK + chunk) * 256 + w * 64 + fm * 16 + l4 * 4 + i] = zz;
            }
    } else if (b < 1424) {
        // --------------- VAL role: 256x128 tile, 16 MFMA/step ---------------
        int vb = b - 480;
        int bx = vb & 7, by = vb >> 3;          // by in [0,118)
        int m0 = by * 256, n0 = bx * 128;
        int wr = w >> 1, wc = w & 1;            // 4x2 waves, per-wave 64x64
        int qa0 = tid, qa1 = tid + 512;
        int ra0 = qa0 >> 2, ca0 = (qa0 & 3) ^ ((ra0 >> 1) & 3);
        int ra1 = qa1 >> 2, ca1 = (qa1 & 3) ^ ((ra1 >> 1) & 3);
        int ga0 = m0 + ra0; if (ga0 > NSEQ - 1) ga0 = NSEQ - 1;
        int ga1 = m0 + ra1; if (ga1 > NSEQ - 1) ga1 = NSEQ - 1;
        const us* pa0 = DENSEP + (ll)(ga0 + FPAD) * 1024 + ca0 * 8;
        const us* pa1 = DENSEP + (ll)(ga1 + FPAD) * 1024 + ca1 * 8;
        int rb_ = tid >> 2, cb_ = (tid & 3) ^ ((rb_ >> 1) & 3);
        const us* pb = WVT + (ll)(n0 + rb_) * 1024 + cb_ * 8;
        int aoff[4], boff[4];
#pragma unroll
        for (int f = 0; f < 4; f++) {
            int row = wr * 64 + f * 16 + l15;
            aoff[f] = row * 32 + ((l4 ^ ((row >> 1) & 3)) << 3);
            int col = wc * 64 + f * 16 + l15;
            boff[f] = 8192 + col * 32 + ((l4 ^ ((col >> 1) & 3)) << 3);
        }
        f32x4 acc[4][4];
#pragma unroll
        for (int i = 0; i < 4; i++)
#pragma unroll
            for (int j = 0; j < 4; j++) acc[i][j] = (f32x4){0.f, 0.f, 0.f, 0.f};

        auto stg = [&](int buf, int kt) {
            int k0 = kt << 5;
            gload16(pa0 + k0, &LDSu[buf + tid * 8]);
            gload16(pa1 + k0, &LDSu[buf + 4096 + tid * 8]);
            gload16(pb + k0, &LDSu[buf + 8192 + tid * 8]);
        };
        stg(0, 0);
        for (int kt = 0; kt < 32; ++kt) {
            int buf = (kt & 1) * 12288;
            if (kt < 31) {
                stg(buf ^ 12288, kt + 1);
                asm volatile("s_waitcnt vmcnt(3)" ::: "memory");
            } else {
                asm volatile("s_waitcnt vmcnt(0)" ::: "memory");
            }
            __builtin_amdgcn_s_barrier();
            asm volatile("" ::: "memory");
            bf16x8 af[4], bfr[4];
#pragma unroll
            for (int f = 0; f < 4; f++) af[f] = *(const bf16x8*)&LDSu[buf + aoff[f]];
#pragma unroll
            for (int f = 0; f < 4; f++) bfr[f] = *(const bf16x8*)&LDSu[buf + boff[f]];
#pragma unroll
            for (int i = 0; i < 4; i++)
#pragma unroll
                for (int j = 0; j < 4; j++)
                    acc[i][j] = __builtin_amdgcn_mfma_f32_16x16x32_bf16(af[i], bfr[j], acc[i][j], 0, 0, 0);
            asm volatile("" ::: "memory");
            __builtin_amdgcn_s_barrier();
            asm volatile("" ::: "memory");
        }
#pragma unroll
        for (int fm = 0; fm < 4; fm++) {
            int rb = m0 + wr * 64 + fm * 16 + l4 * 4;
#pragma unroll
            for (int fn = 0; fn < 4; fn++) {
                int c = n0 + wc * 64 + fn * 16 + l15;
                float bias = wvb[c];
#pragma unroll
                for (int i = 0; i < 4; i++) {
                    int r = rb + i;
                    if (r < NSEQ) VALB[(ll)r * 1024 + c] = f2b(acc[fm][fn][i] + bias);
                }
            }
        }
    } else if (b < 3312) {
        // ---------------- attn1 softmax role (pinv-independent) ----------------
        int idx = b - 1424;
        int h = idx & 7, rc = idx >> 3;          // rc 0..235
        int rb0 = rc * 128 + w * 16;             // this wave's 16 rows
        const us* Qhh = Qh + (ll)h * NPAD * 64;
        const us* KLh = KLB + (ll)h * 16384;
        us* P1h = P1 + (ll)h * NPAD * 256;

        int ra = rb0 + l15; if (ra > NSEQ - 1) ra = NSEQ - 1;
        bf16x8 aq0 = *(const bf16x8*)&Qhh[(ll)(ra + FPAD) * 64 + l4 * 8];
        bf16x8 aq1 = *(const bf16x8*)&Qhh[(ll)(ra + FPAD) * 64 + l4 * 8 + 32];

        f32x4 s[16];
#pragma unroll
        for (int fn = 0; fn < 16; fn++) s[fn] = (f32x4){0.f,0.f,0.f,0.f};
#pragma unroll
        for (int fn = 0; fn < 16; fn++) {
            bf16x8 bk0 = *(const bf16x8*)&KLh[(fn * 16 + l15) * 64 + l4 * 8];
            bf16x8 bk1 = *(const bf16x8*)&KLh[(fn * 16 + l15) * 64 + l4 * 8 + 32];
            s[fn] = __builtin_amdgcn_mfma_f32_16x16x32_bf16(aq0, bk0, s[fn], 0, 0, 0);
            s[fn] = __builtin_amdgcn_mfma_f32_16x16x32_bf16(aq1, bk1, s[fn], 0, 0, 0);
        }
#pragma unroll
        for (int i = 0; i < 4; i++) {
            float m = s[0][i];
#pragma unroll
            for (int fn = 1; fn < 16; fn++) m = fmaxf(m, s[fn][i]);
            m = fmaxf(m, __shfl_xor(m, 1, 64)); m = fmaxf(m, __shfl_xor(m, 2, 64));
            m = fmaxf(m, __shfl_xor(m, 4, 64)); m = fmaxf(m, __shfl_xor(m, 8, 64));
            float sum = 0.f;
#pragma unroll
            for (int fn = 0; fn < 16; fn++) {
                float e = __expf(s[fn][i] - m);
                s[fn][i] = e; sum += e;
            }
            sum += __shfl_xor(sum, 1, 64); sum += __shfl_xor(sum, 2, 64);
            sum += __shfl_xor(sum, 4, 64); sum += __shfl_xor(sum, 8, 64);
            float rinv = 1.0f / sum;
#pragma unroll
            for (int fn = 0; fn < 16; fn++) s[fn][i] *= rinv;
        }
#pragma unroll
        for (int i = 0; i < 4; i++) {
            int r = rb0 + l4 * 4 + i;
            if (r < NSEQ) {
#pragma unroll
                for (int fn = 0; fn < 16; fn++)
                    P1h[(ll)r * 256 + fn * 16 + l15] = f2b(s[fn][i]);
            }
        }
    } else {
        // ------------------------- conv role -------------------------
        int cc = b - 3312;
        int h = cc & 7, ig = cc >> 3;
        int i = ig * 16 + w * 2 + (lane >> 5);
        int d0 = (lane & 31) * 2;
        if (i >= NSEQ) return;
        const us* Vh2 = Vh + (ll)h * NPAD * 64;
        int n0 = FPAD + i - 16;
        float s0 = 0.f, s1 = 0.f;
#pragma unroll
        for (int kk = 0; kk < 33; ++kk) {
            int n = n0 + kk;
            if (n < NPAD) {
                float wgt = cw[h * 33 + kk];
                uint32 v2 = *(const uint32*)&Vh2[(ll)n * 64 + d0];
                s0 = fmaf(wgt, b2f((us)(v2 & 0xffff)), s0);
                s1 = fmaf(wgt, b2f((us)(v2 >> 16)), s1);
            }
        }
        uint32 o = (uint32)f2b(s0) | ((uint32)f2b(s1) << 16);
        *(uint32*)&ATTP[(ll)i * INNER + h * 64 + d0] = o;
    }
}

// ---------------------------------------------------------------------------
// fp32 GEMM (attn2). TB=1: C=A@B^T. EPI 0: C=alpha*acc.
#define BM 128
#define BN 64
#define BK 16
template<int TB, int EPI>
__global__ __launch_bounds__(256)
void gemm_k(const float* __restrict__ A, const float* __restrict__ B, float* __restrict__ C,
            int Mm, int Nn, int Kk, int lda, int ldb, int ldc,
            ll sA, ll sB, ll sC, float alpha, float diagv)
{
    __shared__ float As[BK][132];
    __shared__ float Bs[BK][68];
    int batch = blockIdx.z;
    A += (ll)batch * sA; B += (ll)batch * sB; C += (ll)batch * sC;
    int m0 = blockIdx.y * BM, n0 = blockIdx.x * BN;
    int tid = threadIdx.x, tx = tid & 15, ty = tid >> 4;
    int arow_t = tid >> 1, akh = (tid & 1) * 8;
    bool avalid = (m0 + arow_t < Mm);
    const float* Arow = A + (ll)(m0 + arow_t) * lda;
    float acc[8][4];
#pragma unroll
    for (int i = 0; i < 8; i++)
#pragma unroll
        for (int j = 0; j < 4; j++) acc[i][j] = 0.f;
    for (int kt = 0; kt < Kk / BK; ++kt) {
        int k0 = kt * BK;
        float4 av0 = make_float4(0, 0, 0, 0), av1 = av0;
        if (avalid) {
            av0 = *(const float4*)(Arow + k0 + akh);
            av1 = *(const float4*)(Arow + k0 + akh + 4);
        }
        float4 bv;
        if (TB == 0) bv = *(const float4*)(B + (ll)(k0 + (tid >> 4)) * ldb + n0 + (tid & 15) * 4);
        else         bv = *(const float4*)(B + (ll)(n0 + (tid >> 2)) * ldb + k0 + (tid & 3) * 4);
        __syncthreads();
        As[akh + 0][arow_t] = av0.x; As[akh + 1][arow_t] = av0.y;
        As[akh + 2][arow_t] = av0.z; As[akh + 3][arow_t] = av0.w;
        As[akh + 4][arow_t] = av1.x; As[akh + 5][arow_t] = av1.y;
        As[akh + 6][arow_t] = av1.z; As[akh + 7][arow_t] = av1.w;
        if (TB == 0) *(float4*)&Bs[tid >> 4][(tid & 15) * 4] = bv;
        else {
            int bk4 = (tid & 3) * 4, bn = tid >> 2;
            Bs[bk4 + 0][bn] = bv.x; Bs[bk4 + 1][bn] = bv.y;
            Bs[bk4 + 2][bn] = bv.z; Bs[bk4 + 3][bn] = bv.w;
        }
        __syncthreads();
#pragma unroll
        for (int kk = 0; kk < BK; kk++) {
            float ar[8], br[4];
            *(float4*)&ar[0] = *(const float4*)&As[kk][ty * 8];
            *(float4*)&ar[4] = *(const float4*)&As[kk][ty * 8 + 4];
            *(float4*)&br[0] = *(const float4*)&Bs[kk][tx * 4];
#pragma unroll
            for (int i = 0; i < 8; i++)
#pragma unroll
                for (int j = 0; j < 4; j++) acc[i][j] = fmaf(ar[i], br[j], acc[i][j]);
        }
    }
    int c0 = n0 + tx * 4;
#pragma unroll
    for (int i = 0; i < 8; i++) {
        int r = m0 + ty * 8 + i;
        if (r >= Mm) continue;
#pragma unroll
        for (int j = 0; j < 4; j++) {
            int c = c0 + j;
            if (c >= Nn) continue;
            if (EPI == 0) C[(ll)r * ldc + c] = alpha * acc[i][j];
        }
    }
}

__global__ void kv_reduce2(const us* __restrict__ KVPb, const float* __restrict__ ZP,
                           float* __restrict__ KV)
{
    int e = blockIdx.x * 256 + threadIdx.x;   // < 131072
    int h = e >> 14, r = (e >> 6) & 255;
    float s = 0.f, z = 0.f;
    for (int c = 0; c < NCHUNK; ++c) {
        s += b2f(KVPb[((ll)h * NCHUNK + c) * 16384 + (e & 16383)]);
        z += ZP[((ll)h * NCHUNK + c) * 256 + r];
    }
    KV[e] = s / z;
}

// ---------------------------------------------------------------------------
// pw_fused: PWT[h][c][r] = (pinv Z @ KV)[r][c].
__global__ __launch_bounds__(256)
void pw_fused(const us* __restrict__ ZNf, const float* __restrict__ KV,
              us* __restrict__ PWT)
{
    __shared__ us KT[64 * 264];
    int h = blockIdx.x;
    int tid = threadIdx.x, w = tid >> 6, lane = tid & 63;
    int l15 = lane & 15, l4 = lane >> 4;
    const float* KVh = KV + (ll)h * 16384;
#pragma unroll
    for (int i = 0; i < 64; ++i) {
        int idx = i * 256 + tid;
        int r = idx >> 6, c = idx & 63;
        KT[c * 264 + r] = f2b(KVh[idx]);
    }
    __syncthreads();
    const us* Zh = ZNf + ((ll)h << 16);
    f32x4 acc[4][4];
#pragma unroll
    for (int i = 0; i < 4; i++)
#pragma unroll
        for (int j = 0; j < 4; j++) acc[i][j] = (f32x4){0.f, 0.f, 0.f, 0.f};
    int rw = w * 64;
    for (int ks = 0; ks < 8; ++ks) {
        int k0 = ks * 32 + l4 * 8;
        bf16x8 af[4], bfr[4];
#pragma unroll
        for (int f = 0; f < 4; f++)
            af[f] = *(const bf16x8*)&Zh[(ll)(rw + f * 16 + l15) * 256 + k0];
#pragma unroll
        for (int f = 0; f < 4; f++)
            bfr[f] = *(const bf16x8*)&KT[(f * 16 + l15) * 264 + k0];
#pragma unroll
        for (int i = 0; i < 4; i++)
#pragma unroll
            for (int j = 0; j < 4; j++)
                acc[i][j] = __builtin_amdgcn_mfma_f32_16x16x32_bf16(af[i], bfr[j], acc[i][j], 0, 0, 0);
    }
    us* PWh = PWT + (ll)h * 16384;
#pragma unroll
    for (int fm = 0; fm < 4; fm++)
#pragma unroll
        for (int fn = 0; fn < 4; fn++)
#pragma unroll
            for (int i = 0; i < 4; i++) {
                int r = rw + fm * 16 + l4 * 4 + i;
                int c = fn * 16 + l15;
                PWh[c * 256 + r] = f2b(acc[fm][fn][i]);
            }
}

// ---------------------------------------------------------------------------
// attn1 PV: ATTP[r, h*64+d] += (P1[h] @ PW[h])  (conv residual in ATTP, RMW)
__global__ __launch_bounds__(256)
void attn1_pv(const us* __restrict__ P1, const us* __restrict__ PWT,
              us* __restrict__ ATTP)
{
    int h = blockIdx.y, r0 = blockIdx.x * 128;
    int w = threadIdx.x >> 6, lane = threadIdx.x & 63;
    int l15 = lane & 15, l4 = lane >> 4;
    const us* P1h = P1 + (ll)h * NPAD * 256;
    const us* PWh = PWT + (ll)h * 16384;

    int ra[2];
#pragma unroll
    for (int fm = 0; fm < 2; fm++) {
        int r = r0 + w * 32 + fm * 16 + l15;
        ra[fm] = (r > NSEQ - 1) ? (NSEQ - 1) : r;
    }
    f32x4 acc[2][4];
#pragma unroll
    for (int a = 0; a < 2; a++)
#pragma unroll
        for (int bq = 0; bq < 4; bq++) acc[a][bq] = (f32x4){0.f,0.f,0.f,0.f};

#pragma unroll
    for (int ks = 0; ks < 8; ++ks) {
        bf16x8 ap[2];
#pragma unroll
        for (int fm = 0; fm < 2; fm++)
            ap[fm] = *(const bf16x8*)&P1h[(ll)ra[fm] * 256 + ks * 32 + l4 * 8];
#pragma unroll
        for (int fn = 0; fn < 4; fn++) {
            bf16x8 bp = *(const bf16x8*)&PWh[(fn * 16 + l15) * 256 + ks * 32 + l4 * 8];
            acc[0][fn] = __builtin_amdgcn_mfma_f32_16x16x32_bf16(ap[0], bp, acc[0][fn], 0, 0, 0);
            acc[1][fn] = __builtin_amdgcn_mfma_f32_16x16x32_bf16(ap[1], bp, acc[1][fn], 0, 0, 0);
        }
    }
#pragma unroll
    for (int fm = 0; fm < 2; fm++)
#pragma unroll
        for (int fn = 0; fn < 4; fn++)
#pragma unroll
            for (int i = 0; i < 4; i++) {
                int r = r0 + w * 32 + fm * 16 + l4 * 4 + i;
                if (r < NSEQ) {
                    ll idx = (ll)r * 512 + h * 64 + fn * 16 + l15;
                    float a = acc[fm][fn][i] + b2f(ATTP[idx]);
                    ATTP[idx] = f2b(a);
                }
            }
}

// ---------------------------------------------------------------------------
__global__ void trans_f2b(const float* __restrict__ in, us* __restrict__ out,
                          int R, int Cc, ll sI, ll sO)
{
    __shared__ float tile[32][33];
    const float* inp = in + (ll)blockIdx.z * sI;
    us* outp = out + (ll)blockIdx.z * sO;
    int r0 = blockIdx.y * 32, c0 = blockIdx.x * 32;
    int tx = threadIdx.x & 31, ty = threadIdx.x >> 5;
#pragma unroll
    for (int i = 0; i < 4; i++) {
        int r = r0 + ty + i * 8, c = c0 + tx;
        tile[ty + i * 8][tx] = (r < R && c < Cc) ? inp[(ll)r * Cc + c] : 0.f;
    }
    __syncthreads();
#pragma unroll
    for (int i = 0; i < 4; i++) {
        int c = c0 + ty + i * 8, r = r0 + tx;
        if (c < Cc && r < R) outp[(ll)c * R + r] = f2b(tile[tx][ty + i * 8]);
    }
}

__global__ void trans_b2b(const us* __restrict__ in, us* __restrict__ out,
                          int R, int Cc, ll sI, ll sO)
{
    __shared__ us tile[32][34];
    const us* inp = in + (ll)blockIdx.z * sI;
    us* outp = out + (ll)blockIdx.z * sO;
    int r0 = blockIdx.y * 32, c0 = blockIdx.x * 32;
    int tx = threadIdx.x & 31, ty = threadIdx.x >> 5;
#pragma unroll
    for (int i = 0; i < 4; i++) {
        int r = r0 + ty + i * 8, c = c0 + tx;
        tile[ty + i * 8][tx] = (r < R && c < Cc) ? inp[(ll)r * Cc + c] : (us)0;
    }
    __syncthreads();
#pragma unroll
    for (int i = 0; i < 4; i++) {
        int c = c0 + ty + i * 8, r = r0 + tx;
        if (c < Cc && r < R) outp[(ll)c * R + r] = tile[tx][ty + i * 8];
    }
}

__global__ void dense_pad_b(const float* __restrict__ x, us* __restrict__ o)
{
    ll e4 = ((ll)blockIdx.x * 256 + threadIdx.x) * 4;
    int r = (int)(e4 >> 10), c = (int)(e4 & 1023);
    ushort4 u;
    if (r < FPAD) { u.x = u.y = u.z = u.w = 0; }
    else {
        float4 v = *(const float4*)&x[(ll)(r - FPAD) * 1024 + c];
        u.x = f2b(v.x); u.y = f2b(v.y); u.z = f2b(v.z); u.w = f2b(v.w);
    }
    *(ushort4*)&o[e4] = u;
}

__global__ void concat_bias(const float* __restrict__ a, const float* __restrict__ b,
                            float* __restrict__ o)
{
    int t = threadIdx.x;
    o[t] = a[t]; o[256 + t] = b[t];
}

__global__ void landmark_mean_b(const us* __restrict__ src, float* __restrict__ dst,
                                us* __restrict__ dstb)
{
    int b = blockIdx.x;
    int h = b >> 8, jm = b & 255;
    int d = threadIdx.x;
    const us* p = src + ((ll)h * NPAD + (ll)jm * LCHUNK) * DHEAD + d;
    float s = 0.f;
    for (int jl = 0; jl < LCHUNK; ++jl) s += b2f(p[jl * DHEAD]);
    float v = s * (1.0f / LCHUNK);
    dst[((h << 8) + jm) * DHEAD + d] = v;
    dstb[((h << 8) + jm) * DHEAD + d] = f2b(v);
}

__global__ void rowsoftmax256(float* __restrict__ X)
{
    __shared__ float red[256];
    float* p = X + (ll)blockIdx.x * 256;
    int t = threadIdx.x;
    float v = p[t];
    red[t] = v; __syncthreads();
    for (int s = 128; s > 0; s >>= 1) { if (t < s) red[t] = fmaxf(red[t], red[t + s]); __syncthreads(); }
    float m = red[0]; __syncthreads();
    float e = expf(v - m);
    red[t] = e; __syncthreads();
    for (int s = 128; s > 0; s >>= 1) { if (t < s) red[t] += red[t + s]; __syncthreads(); }
    p[t] = e / red[0];
}

__global__ void colrow_max(const float* __restrict__ A2, float* __restrict__ hm)
{
    __shared__ float red[256];
    int h = blockIdx.x, t = threadIdx.x;
    const float* X = A2 + (ll)h * LM * LM;
    float cs = 0.f;
    for (int i = 0; i < LM; ++i) cs += X[i * LM + t];
    red[t] = cs; __syncthreads();
    for (int s = 128; s > 0; s >>= 1) { if (t < s) red[t] = fmaxf(red[t], red[t + s]); __syncthreads(); }
    if (t == 0) hm[h] = red[0];
    __syncthreads();
    float rs = 0.f;
    const float* Xr = X + (ll)t * LM;
    for (int j = 0; j < LM; ++j) rs += Xr[j];
    red[t] = rs; __syncthreads();
    for (int s = 128; s > 0; s >>= 1) { if (t < s) red[t] = fmaxf(red[t], red[t + s]); __syncthreads(); }
    if (t == 0) hm[8 + h] = red[0];
}

__global__ void denom_fin(const float* __restrict__ hm, float* __restrict__ scal)
{
    float cm = hm[0], rm = hm[8];
    for (int h = 1; h < 8; ++h) { cm = fmaxf(cm, hm[h]); rm = fmaxf(rm, hm[8 + h]); }
    scal[0] = 1.0f / (cm * rm);
}

__global__ void pinv_init(const float* __restrict__ A2, const float* __restrict__ scal,
                          us* __restrict__ XN, us* __restrict__ ZN, us* __restrict__ ZT)
{
    ll e = (ll)blockIdx.x * 256 + threadIdx.x;
    int h = (int)(e >> 16), r = (int)(e >> 8) & 255, c = (int)e & 255;
    float v = A2[e];
    XN[e] = f2b(v);
    float vs = v * scal[0];
    ZT[e] = f2b(vs);
    ZN[((ll)h << 16) + ((ll)c << 8) + r] = f2b(vs);
}

__global__ void zero_f32(float* __restrict__ p, int n)
{
    int i = blockIdx.x * 256 + threadIdx.x;
    if (i < n) p[i] = 0.f;
}

__global__ void edge_scores_b(const int* __restrict__ ei, const float* __restrict__ adj,
                              const us* __restrict__ qk2, float* __restrict__ Araw, int E)
{
    int gw = (blockIdx.x * 256 + threadIdx.x) >> 6;
    int lane = threadIdx.x & 63;
    if (gw >= E) return;
    int src = ei[gw], dst = ei[E + gw];
    const uint32* qp = (const uint32*)(qk2 + (ll)src * 512);
    const uint32* kp = (const uint32*)(qk2 + (ll)dst * 512 + 256);
    float acc = 0.f;
#pragma unroll
    for (int t = 0; t < 2; t++) {
        uint32 qu = qp[lane + t * 64], ku = kp[lane + t * 64];
        acc += b2f((us)(qu & 0xffff)) * b2f((us)(ku & 0xffff));
        acc += b2f((us)(qu >> 16)) * b2f((us)(ku >> 16));
    }
#pragma unroll
    for (int m = 32; m >= 1; m >>= 1) acc += __shfl_xor(acc, m, 64);
    if (lane == 0) atomicAdd(Araw + src, acc * adj[gw] * 0.0625f);
}

__global__ void softmax30k_stats(const float* __restrict__ A, float* __restrict__ scal)
{
    __shared__ float red[1024];
    int t = threadIdx.x;
    float m = -3.0e38f;
    for (int i = t; i < NSEQ; i += 1024) m = fmaxf(m, A[i]);
    red[t] = m; __syncthreads();
    for (int s = 512; s > 0; s >>= 1) { if (t < s) red[t] = fmaxf(red[t], red[t + s]); __syncthreads(); }
    m = red[0]; __syncthreads();
    float sum = 0.f;
    for (int i = t; i < NSEQ; i += 1024) sum += expf(A[i] - m);
    red[t] = sum; __syncthreads();
    for (int s = 512; s > 0; s >>= 1) { if (t < s) red[t] += red[t + s]; __syncthreads(); }
    if (t == 0) { scal[1] = m; scal[2] = red[0]; }
}

// xo = gate(alpha(Araw)*val, enc); alpha computed inline (one row per block)
__global__ void gate_kernel(const float* __restrict__ Araw, const float* __restrict__ scal,
                            const us* __restrict__ VALB, const us* __restrict__ ENCB,
                            float* __restrict__ OUT)
{
    ll e4 = ((ll)blockIdx.x * 256 + threadIdx.x) * 4;
    int i = (int)(e4 >> 10);
    float a = __expf(Araw[i] - scal[1]) / scal[2];
    ushort4 vv = *(const ushort4*)&VALB[e4];
    ushort4 ee = *(const ushort4*)&ENCB[e4];
    float4 o;
    float* op = &o.x;
    const us* vp = (const us*)&vv;
    const us* ep = (const us*)&ee;
#pragma unroll
    for (int j = 0; j < 4; j++) {
        float xl = a * b2f(vp[j]);
        float sg = 1.0f / (1.0f + __expf(xl));
        float sw = sg * sg;
        op[j] = xl * 2.0f * sw + 2.0f * b2f(ep[j]) * (1.0f - sw);
    }
    *(float4*)&OUT[e4] = o;
}

// ---------------------------------------------------------------------------
extern "C" void kernel_launch(void* const* d_in, const int* in_sizes, int n_in,
                              void* d_out, int out_size, void* d_ws, size_t ws_size,
                              hipStream_t stream)
{
    const float* dense  = (const float*)d_in[0];
    const int*   ei     = (const int*)d_in[1];
    const float* adj    = (const float*)d_in[2];
    const float* qkv_w  = (const float*)d_in[3];
    const float* out_w  = (const float*)d_in[4];
    const float* out_b  = (const float*)d_in[5];
    const float* conv_w = (const float*)d_in[6];
    const float* wq_w   = (const float*)d_in[7];
    const float* wq_b   = (const float*)d_in[8];
    const float* wk_w   = (const float*)d_in[9];
    const float* wk_b   = (const float*)d_in[10];
    const float* wv_w   = (const float*)d_in[11];
    const float* wv_b   = (const float*)d_in[12];
    int E = in_sizes[2];

    char* w = (char*)d_ws;
    auto alloc = [&](ll bytes) { char* p = w; w += (bytes + 255) & ~(ll)255; return p; };

    us*    DENSEP = (us*)alloc((ll)NPAD * 1024 * 2);
    us*    QKVH   = (us*)alloc((ll)3 * 8 * NPAD * 64 * 2);
    us*    ENCB   = QKVH;                         // alias: Qh+Kh dead before out-proj writes ENCB
    us*    Qh = QKVH, *Kh = QKVH + (ll)8 * NPAD * 64, *Vh = QKVH + (ll)16 * NPAD * 64;
    us*    VT     = (us*)alloc((ll)8 * 64 * NPAD * 2);
    us*    QKVWT  = (us*)alloc((ll)1536 * 1024 * 2);
    us*    OUTWT  = (us*)alloc((ll)1024 * 512 * 2);
    us*    WQKT   = (us*)alloc((ll)512 * 1024 * 2);
    us*    WVT    = (us*)alloc((ll)1024 * 1024 * 2);
    float* WQKB   = (float*)alloc(512 * 4);
    float* QL     = (float*)alloc((ll)8 * 256 * 64 * 4);
    float* KL     = (float*)alloc((ll)8 * 256 * 64 * 4);
    us*    QLB    = (us*)alloc((ll)8 * 256 * 64 * 2);
    us*    KLB    = (us*)alloc((ll)8 * 256 * 64 * 2);
    float* A2     = (float*)alloc((ll)8 * 65536 * 4);
    us*    XN     = (us*)alloc((ll)8 * 65536 * 2);
    us*    ZN     = (us*)alloc((ll)8 * 65536 * 2);
    us*    ZT     = (us*)alloc((ll)8 * 65536 * 2);
    us*    ZN2    = (us*)alloc((ll)8 * 65536 * 2);
    us*    ZT2    = (us*)alloc((ll)8 * 65536 * 2);
    us*    Ybuf   = (us*)alloc((ll)8 * 65536 * 2);
    us*    W1T    = (us*)alloc((ll)8 * 65536 * 2);
    us*    W2T    = (us*)alloc((ll)8 * 65536 * 2);
    us*    W3T    = (us*)alloc((ll)8 * 65536 * 2);
    us*    KVPb   = (us*)alloc((ll)8 * NCHUNK * 16384 * 2);
    float* ZP     = (float*)alloc((ll)8 * NCHUNK * 256 * 4);
    float* KV     = (float*)alloc((ll)8 * 16384 * 4);
    us*    PWT    = (us*)alloc((ll)8 * 16384 * 2);
    float* HM     = (float*)alloc(64 * 4);
    float* SC     = (float*)alloc(64 * 4);
    us*    ATTP   = (us*)alloc((ll)NSEQ * 512 * 2);
    us*    QK2B   = ATTP;                         // alias: ATTP dead after out-proj
    us*    VALB   = (us*)alloc((ll)NSEQ * 1024 * 2);
    us*    P1     = (us*)alloc((ll)8 * NPAD * 256 * 2);   // attn1 softmax probs

    float* OUT  = (float*)d_out;
    float* ARAW = OUT + (ll)NSEQ * DMODEL;

    // ---- prep
    trans_f2b<<<dim3(48, 32, 1), 256, 0, stream>>>(qkv_w, QKVWT, 1024, 1536, 0, 0);
    trans_f2b<<<dim3(32, 16, 1), 256, 0, stream>>>(out_w, OUTWT, 512, 1024, 0, 0);
    trans_f2b<<<dim3(8, 32, 1), 256, 0, stream>>>(wq_w, WQKT, 1024, 256, 0, 0);
    trans_f2b<<<dim3(8, 32, 1), 256, 0, stream>>>(wk_w, WQKT + (ll)256 * 1024, 1024, 256, 0, 0);
    trans_f2b<<<dim3(32, 32, 1), 256, 0, stream>>>(wv_w, WVT, 1024, 1024, 0, 0);
    concat_bias<<<1, 256, 0, stream>>>(wq_b, wk_b, WQKB);
    dense_pad_b<<<NPAD, 256, 0, stream>>>(dense, DENSEP);

    // ---- QKV projection -> per-head bf16 Q,K,V (q pre-scaled by 1/8)
    bgemm<3><<<dim3(12, 118, 1), 512, 0, stream>>>(DENSEP, QKVWT, nullptr, QKVH,
        nullptr, nullptr, NPAD, 1536, 1024, 1024, 1024, 0, 0, NPAD, 1536, 0);

    // ---- landmarks (fp32 + bf16 in one pass)
    landmark_mean_b<<<2048, 64, 0, stream>>>(Qh, QL, QLB);
    landmark_mean_b<<<2048, 64, 0, stream>>>(Kh, KL, KLB);

    // ---- attn2 (fp32) + denom
    gemm_k<1, 0><<<dim3(4, 2, 8), 256, 0, stream>>>(QL, KL, A2, LM, LM, DHEAD,
        DHEAD, DHEAD, LM, LM * DHEAD, LM * DHEAD, LM * LM, 1.f, 0.f);
    rowsoftmax256<<<2048, 256, 0, stream>>>(A2);
    colrow_max<<<8, 256, 0, stream>>>(A2, HM);
    denom_fin<<<1, 1, 0, stream>>>(HM, SC);
    pinv_init<<<2048, 256, 0, stream>>>(A2, SC, XN, ZN, ZT);

    // ---- V transpose (attn3's B operand) must precede mega
    trans_b2b<<<dim3(2, 944, 8), 256, 0, stream>>>(Vh, VT, NPAD, 64, (ll)NPAD * 64, (ll)64 * NPAD);

    // ---- MEGA: pinv(8) || attn3(472) || VAL(944) || P1(1888) || conv(15000)
    mega1<<<18312, 512, 0, stream>>>(XN, ZN, ZT, ZN2, ZT2, Ybuf, W1T, W2T, W3T,
                                     QLB, Kh, VT, KVPb, ZP, Vh, conv_w, ATTP,
                                     DENSEP, WVT, wv_b, VALB, Qh, KLB, P1);

    // ---- KV reduce -> PWT (fused; NIT=4 even swaps => pinv result in ZN)
    kv_reduce2<<<512, 256, 0, stream>>>(KVPb, ZP, KV);
    pw_fused<<<8, 256, 0, stream>>>(ZN, KV, PWT);

    // ---- attn1 PV (P1 @ PW + conv residual already in ATTP)
    attn1_pv<<<dim3(235, 8), 256, 0, stream>>>(P1, PWT, ATTP);

    // ---- out projection + bias + dense residual -> ENCB bf16 only
    bgemm<12><<<dim3(8, 118, 1), 512, 0, stream>>>(ATTP, OUTWT, nullptr, ENCB,
        out_b, dense, NSEQ, 1024, 512, 512, 512, 1024, 1024, NSEQ, 1024, 0);

    // ---- merged q2|k2 projection (bf16 out, [row][512] layout)
    bgemm<10><<<dim3(4, 118, 1), 512, 0, stream>>>(ENCB, WQKT, nullptr, QK2B,
        WQKB, nullptr, NSEQ, 512, 1024, 1024, 1024, 512, 0, NSEQ, 512, 0);

    // ---- edges -> A_raw -> softmax stats (alpha folded into gate)
    zero_f32<<<(NSEQ + 255) / 256, 256, 0, stream>>>(ARAW, NSEQ);
    edge_scores_b<<<(E + 3) / 4, 256, 0, stream>>>(ei, adj, QK2B, ARAW, E);
    softmax30k_stats<<<1, 1024, 0, stream>>>(ARAW, SC);

    // ---- final gating (reads ARAW + VALB + ENCB, writes xo fp32)
    gate_kernel<<<30000, 256, 0, stream>>>(ARAW, SC, VALB, ENCB, OUT);
}